// Round 20
// baseline (1386.347 us; speedup 1.0000x reference)
//
#include <hip/hip_runtime.h>

typedef __bf16 bf8 __attribute__((ext_vector_type(8)));
typedef float f4 __attribute__((ext_vector_type(4)));
typedef unsigned int u4 __attribute__((ext_vector_type(4)));

// Problem constants (fixed by reference)
constexpr int BSZ = 2, NSEQ = 2048, DIM = 512, NH = 8, DH = 64, INNER = 512;
constexpr int ROWS = BSZ * NSEQ;          // 4096

// Workspace layout (bytes) — d_ws is >=268 MB (harness poison size)
constexpr size_t XB_OFF  = 0;                          // x cast bf16: 4 MB
constexpr size_t WQT_OFF = 4194304;                    // W_qkv^T bf16: 1.5 MB
constexpr size_t WOT_OFF = WQT_OFF + 1572864;          // W_out^T bf16: 0.5 MB
constexpr size_t Q_OFF   = WOT_OFF + 524288;           // Q/8 bf16 [16][2048][64]: 4 MB
constexpr size_t K_OFF   = Q_OFF + 4194304;            // K bf16: 4 MB
constexpr size_t V_OFF   = K_OFF + 4194304;            // V bf16: 4 MB
constexpr size_t AO_OFF  = V_OFF + 4194304;            // attn out bf16 [4096][512]: 4 MB
constexpr size_t CAND_OFF= AO_OFF + 4194304;           // cand u32 [32768][16][16]: 32 MB
constexpr size_t OVF_OFF = CAND_OFF + 33554432;        // ovf u32 [32768]: 128 KB
// total ~60 MB

// ---------------- prep: cast x to bf16; transpose+cast weights; zero ovf flags ----
__global__ __launch_bounds__(256) void prep_kernel(
    const float* __restrict__ x, const float* __restrict__ Wq, const float* __restrict__ Wo,
    __bf16* __restrict__ xb, __bf16* __restrict__ wqt, __bf16* __restrict__ wot,
    unsigned* __restrict__ ovf) {
  int idx = blockIdx.x * 256 + threadIdx.x;
  if (idx < ROWS * DIM) xb[idx] = (__bf16)x[idx];
  if (idx < 3 * INNER * DIM) {            // wqt[n][k] = Wq[k][n]
    int n = idx >> 9, k = idx & 511;
    wqt[idx] = (__bf16)Wq[k * (3 * INNER) + n];
  }
  if (idx < INNER * DIM) {                // wot[n][k] = Wo[k][n]
    int n = idx >> 9, k = idx & 511;
    wot[idx] = (__bf16)Wo[k * DIM + n];
  }
  if (idx < 32768) ovf[idx] = 0;
}

// ---------------- kernel 1: qkv = x @ W_qkv -> Q/8,K,V.  128x128 tile, BK=64, ----
// T14 reg-staged LDS pipeline: issue loads for step k+1 before computing step k.
__global__ __launch_bounds__(256) void qkv_gemm(
    const __bf16* __restrict__ xb, const __bf16* __restrict__ wqt,
    __bf16* __restrict__ Qh, __bf16* __restrict__ Kh, __bf16* __restrict__ Vh) {
  __shared__ __bf16 Asm[128 * 64];          // byte = r*128 + (chbyte ^ ((r&7)<<4))
  __shared__ __bf16 Bsm[128 * 64];
  int bid = blockIdx.x;
  int bn = bid % 12, bm = bid / 12;         // 12 col-tiles x 32 row-tiles of 128
  int t = threadIdx.x, lane = t & 63, wid = t >> 6;
  int wy = wid >> 1, wx = wid & 1;
  int l15 = lane & 15, lg = lane >> 4;
  int sr = t >> 3, sc = t & 7;
  const __bf16* Ag = xb  + (size_t)(bm * 128 + sr) * 512 + sc * 8;
  const __bf16* Bg = wqt + (size_t)(bn * 128 + sr) * 512 + sc * 8;
  int swz = (sc * 16) ^ ((sr & 7) << 4);    // (j*32 preserves r&7)
  bf8 ra[4], rb[4];
#pragma unroll
  for (int j = 0; j < 4; ++j) {
    ra[j] = *(const bf8*)(Ag + (size_t)(j * 32) * 512);
    rb[j] = *(const bf8*)(Bg + (size_t)(j * 32) * 512);
  }
  f4 acc[4][4];
#pragma unroll
  for (int mt = 0; mt < 4; ++mt)
#pragma unroll
    for (int nt = 0; nt < 4; ++nt) acc[mt][nt] = (f4){0.f, 0.f, 0.f, 0.f};

  for (int ks = 0; ks < 8; ++ks) {
    __syncthreads();
#pragma unroll
    for (int j = 0; j < 4; ++j) {
      *(bf8*)((char*)Asm + (size_t)(j * 32 + sr) * 128 + swz) = ra[j];
      *(bf8*)((char*)Bsm + (size_t)(j * 32 + sr) * 128 + swz) = rb[j];
    }
    if (ks < 7) {
      const __bf16* Ag2 = Ag + (ks + 1) * 64;
      const __bf16* Bg2 = Bg + (ks + 1) * 64;
#pragma unroll
      for (int j = 0; j < 4; ++j) {
        ra[j] = *(const bf8*)(Ag2 + (size_t)(j * 32) * 512);
        rb[j] = *(const bf8*)(Bg2 + (size_t)(j * 32) * 512);
      }
    }
    __syncthreads();
#pragma unroll
    for (int kk = 0; kk < 2; ++kk) {
      bf8 af[4], bg[4];
#pragma unroll
      for (int mt = 0; mt < 4; ++mt) {
        int r = wy * 64 + mt * 16 + l15;
        af[mt] = *(const bf8*)((const char*)Asm + (size_t)r * 128 +
                               ((kk * 64 + lg * 16) ^ ((r & 7) << 4)));
      }
#pragma unroll
      for (int nt = 0; nt < 4; ++nt) {
        int r = wx * 64 + nt * 16 + l15;
        bg[nt] = *(const bf8*)((const char*)Bsm + (size_t)r * 128 +
                               ((kk * 64 + lg * 16) ^ ((r & 7) << 4)));
      }
#pragma unroll
      for (int mt = 0; mt < 4; ++mt)
#pragma unroll
        for (int nt = 0; nt < 4; ++nt)
          acc[mt][nt] = __builtin_amdgcn_mfma_f32_16x16x32_bf16(af[mt], bg[nt], acc[mt][nt], 0, 0, 0);
    }
  }
#pragma unroll
  for (int mt = 0; mt < 4; ++mt)
#pragma unroll
    for (int nt = 0; nt < 4; ++nt) {
      int col = bn * 128 + wx * 64 + nt * 16 + l15;
      int which = col >> 9;                  // 0=q 1=k 2=v
      int inner = col & 511;
      int h = inner >> 6, d = inner & 63;
      __bf16* dst = which == 0 ? Qh : (which == 1 ? Kh : Vh);
      float scale = which == 0 ? 0.125f : 1.0f;
#pragma unroll
      for (int i = 0; i < 4; ++i) {
        int row = bm * 128 + wy * 64 + mt * 16 + lg * 4 + i;
        int b = row >> 11, n = row & 2047;
        dst[(((size_t)(b * 8 + h)) * 2048 + n) * 64 + d] = (__bf16)(acc[mt][nt][i] * scale);
      }
    }
}

// ---------------- kernel 2a: QK^T -> compact candidate lists (NO S matrix) ----
// Per (row, col-block of 128): emit candidates z > bmax_block - 1.01 packed as
// (f16(z)<<16)|k into 16 fixed slots (pad 0xFC000000 = -inf). Safe discard proof:
// z <= bmax_blk-1.01 => f16(z) <= z+0.002 <= bmax_blk-1.008 <= gmax-1.008
//   <= (gmax_f16+0.002)-1.008 = gmax_f16-1.006 < gmax_f16-1 <= tau*.
__global__ __launch_bounds__(256) void qk_gemm(
    const __bf16* __restrict__ Qh, const __bf16* __restrict__ Kh,
    unsigned* __restrict__ cand, unsigned* __restrict__ ovf) {
  __shared__ char lds[16384];               // K-tile [128][64] bf16, swizzled
  int bid = blockIdx.x;
  int lin = (bid & 7) * 512 + (bid >> 3);   // bijective XCD swizzle (4096 % 8 == 0)
  int bh = lin >> 8;                        // head 0..15
  int rt = (lin >> 4) & 15;                 // q row-tile (128)
  int colt = lin & 15;                      // k col-tile (128)
  int t = threadIdx.x, lane = t & 63, wid = t >> 6;
  int l15 = lane & 15, lg = lane >> 4;

  {
    int sr = t >> 3, sc = t & 7;            // 32 rows/pass, full 128B rows coalesced
    const __bf16* Kg = Kh + ((size_t)bh * 2048 + colt * 128 + sr) * 64 + sc * 8;
    bf8 k0 = *(const bf8*)(Kg);
    bf8 k1 = *(const bf8*)(Kg + 32 * 64);
    bf8 k2 = *(const bf8*)(Kg + 64 * 64);
    bf8 k3 = *(const bf8*)(Kg + 96 * 64);
    int swz = (sc * 16) ^ ((sr & 7) << 4);
    *(bf8*)(lds + (size_t)sr * 128 + swz) = k0;
    *(bf8*)(lds + (size_t)(sr + 32) * 128 + swz) = k1;
    *(bf8*)(lds + (size_t)(sr + 64) * 128 + swz) = k2;
    *(bf8*)(lds + (size_t)(sr + 96) * 128 + swz) = k3;
  }
  const __bf16* Qp = Qh + ((size_t)bh * 2048 + rt * 128 + wid * 32) * 64;
  bf8 aA0 = *(const bf8*)(Qp + l15 * 64 + lg * 8);
  bf8 aA1 = *(const bf8*)(Qp + l15 * 64 + 32 + lg * 8);
  bf8 aB0 = *(const bf8*)(Qp + (16 + l15) * 64 + lg * 8);
  bf8 aB1 = *(const bf8*)(Qp + (16 + l15) * 64 + 32 + lg * 8);
  __syncthreads();                          // K-tile ready

  f4 acc[2][8];
#pragma unroll
  for (int s = 0; s < 2; ++s)
#pragma unroll
    for (int j = 0; j < 8; ++j) acc[s][j] = (f4){0.f, 0.f, 0.f, 0.f};
#pragma unroll
  for (int ctj = 0; ctj < 8; ++ctj) {
    int r = ctj * 16 + l15;
    const char* kb = lds + (size_t)r * 128;
    int sw = (r & 7) << 4;
    bf8 b0 = *(const bf8*)(kb + ((lg * 16) ^ sw));
    bf8 b1 = *(const bf8*)(kb + ((64 + lg * 16) ^ sw));
    acc[0][ctj] = __builtin_amdgcn_mfma_f32_16x16x32_bf16(aA0, b0, acc[0][ctj], 0, 0, 0);
    acc[0][ctj] = __builtin_amdgcn_mfma_f32_16x16x32_bf16(aA1, b1, acc[0][ctj], 0, 0, 0);
    acc[1][ctj] = __builtin_amdgcn_mfma_f32_16x16x32_bf16(aB0, b0, acc[1][ctj], 0, 0, 0);
    acc[1][ctj] = __builtin_amdgcn_mfma_f32_16x16x32_bf16(aB1, b1, acc[1][ctj], 0, 0, 0);
  }
  // extraction: per (s,i) the 64-lane ballot covers 4 rows (lg segments of 16 lanes)
  unsigned lm15 = (1u << l15) - 1;
#pragma unroll
  for (int s = 0; s < 2; ++s)
#pragma unroll
    for (int i = 0; i < 4; ++i) {
      float rm = acc[s][0][i];
#pragma unroll
      for (int ctj = 1; ctj < 8; ++ctj) rm = fmaxf(rm, acc[s][ctj][i]);
#pragma unroll
      for (int o = 1; o < 16; o <<= 1) rm = fmaxf(rm, __shfl_xor(rm, o));
      float thr = rm - 1.01f;
      int rowg = bh * 2048 + rt * 128 + wid * 32 + s * 16 + lg * 4 + i;
      unsigned* grp = cand + ((size_t)rowg << 8) + colt * 16;
      int base = 0;
#pragma unroll
      for (int ctj = 0; ctj < 8; ++ctj) {
        float zf = acc[s][ctj][i];
        bool c = zf > thr;
        unsigned long long b = __ballot(c);
        unsigned seg = (unsigned)((b >> (lg * 16)) & 0xFFFFu);
        if (c) {
          int slot = base + __popc(seg & lm15);
          if (slot < 16) {
            _Float16 hv = (_Float16)zf;
            unsigned short hb = __builtin_bit_cast(unsigned short, hv);
            grp[slot] = ((unsigned)hb << 16) | (unsigned)(colt * 128 + ctj * 16 + l15);
          }
        }
        base += __popc(seg);
      }
      if (l15 >= base && l15 < 16) grp[l15] = 0xFC000000u;   // -inf pad
      if (base > 16 && l15 == 0) ovf[rowg] = 1;
    }
}

// ---------------- kernel 2b: sparsemax + sparse PV from candidate lists ----
// One wave per row: 1KB dense read (4 u32/lane), Michelot on candidates (exact:
// candidates superset of support), ballot gather of survivors.
__global__ __launch_bounds__(512, 8) void sparse_pv(
    const unsigned* __restrict__ cand, const __bf16* __restrict__ Vh,
    __bf16* __restrict__ AO) {
  int lane = threadIdx.x & 63, wid = threadIdx.x >> 6;   // 8 waves
  int rowid = blockIdx.x * 8 + wid;         // 0..32767
  int bh = rowid >> 11, n = rowid & 2047;
  const unsigned* cr = cand + ((size_t)rowid << 8);
  const __bf16* Vp = Vh + (size_t)bh * 2048 * 64;

  u4 w = *(const u4*)(cr + lane * 4);       // 4 packed candidates per lane
  float v0, v1, v2, v3;
  {
    unsigned short h0 = (unsigned short)(w[0] >> 16);
    unsigned short h1 = (unsigned short)(w[1] >> 16);
    unsigned short h2v = (unsigned short)(w[2] >> 16);
    unsigned short h3 = (unsigned short)(w[3] >> 16);
    v0 = (float)__builtin_bit_cast(_Float16, h0);
    v1 = (float)__builtin_bit_cast(_Float16, h1);
    v2 = (float)__builtin_bit_cast(_Float16, h2v);
    v3 = (float)__builtin_bit_cast(_Float16, h3);
  }
  int j0 = w[0] & 2047, j1 = w[1] & 2047, j2 = w[2] & 2047, j3 = w[3] & 2047;

  // global max over candidates (pads are -inf)
  float mx = fmaxf(fmaxf(v0, v1), fmaxf(v2, v3));
#pragma unroll
  for (int o = 32; o; o >>= 1) mx = fmaxf(mx, __shfl_xor(mx, o));

  float tau = mx - 1.0f, cprev = -1.0f;
  for (int it = 0; it < 16; ++it) {
    float s = 0.f, c = 0.f;
    if (v0 > tau) { s += v0; c += 1.f; }
    if (v1 > tau) { s += v1; c += 1.f; }
    if (v2 > tau) { s += v2; c += 1.f; }
    if (v3 > tau) { s += v3; c += 1.f; }
#pragma unroll
    for (int o = 32; o; o >>= 1) { s += __shfl_xor(s, o); c += __shfl_xor(c, o); }
    if (c == cprev) break;
    tau = (s - 1.0f) / c; cprev = c;
  }
  float acc_o = 0.f;
  float p0 = v0 - tau, p1 = v1 - tau, p2 = v2 - tau, p3 = v3 - tau;
#pragma unroll
  for (int q = 0; q < 4; ++q) {
    float p = q == 0 ? p0 : (q == 1 ? p1 : (q == 2 ? p2 : p3));
    int jj = q == 0 ? j0 : (q == 1 ? j1 : (q == 2 ? j2 : j3));
    unsigned long long m = __ballot(p > 0.f);
    while (m) {
      int src = __ffsll((long long)m) - 1;
      m &= m - 1;
      float pj = __shfl(p, src);
      int j = __shfl(jj, src);
      acc_o += pj * (float)Vp[(size_t)j * 64 + lane];
    }
  }
  int rowg = (bh >> 3) * 2048 + n;          // [B][N] row
  AO[(size_t)rowg * 512 + (bh & 7) * 64 + lane] = (__bf16)acc_o;
}

// ---------------- kernel 2c: exact fallback for overflowed rows (rare) ----
__global__ __launch_bounds__(512) void sparse_fb(
    const __bf16* __restrict__ Qh, const __bf16* __restrict__ Kh,
    const __bf16* __restrict__ Vh, __bf16* __restrict__ AO,
    const unsigned* __restrict__ ovf) {
  int lane = threadIdx.x & 63, wid = threadIdx.x >> 6;
  for (int rowid = blockIdx.x * 8 + wid; rowid < 32768; rowid += gridDim.x * 8) {
    if (ovf[rowid] == 0) continue;
    int bh = rowid >> 11, n = rowid & 2047;
    const __bf16* qp = Qh + ((size_t)bh * 2048 + n) * 64;
    bf8 qv[8];
#pragma unroll
    for (int j = 0; j < 8; ++j) qv[j] = *(const bf8*)(qp + j * 8);
    const __bf16* Kp = Kh + (size_t)bh * 2048 * 64;
    const __bf16* Vp = Vh + (size_t)bh * 2048 * 64;
    float z[32];
    for (int kk = 0; kk < 32; ++kk) {
      const __bf16* kr = Kp + (size_t)(kk * 64 + lane) * 64;
      float d = 0.f;
#pragma unroll
      for (int j = 0; j < 8; ++j) {
        bf8 kv = *(const bf8*)(kr + j * 8);
#pragma unroll
        for (int e = 0; e < 8; ++e) d += (float)qv[j][e] * (float)kv[e];
      }
      z[kk] = d;
    }
    float mx = z[0];
#pragma unroll
    for (int kk = 1; kk < 32; ++kk) mx = fmaxf(mx, z[kk]);
#pragma unroll
    for (int o = 32; o; o >>= 1) mx = fmaxf(mx, __shfl_xor(mx, o));
    float tau = mx - 1.0f, cprev = -1.0f;
    for (int it = 0; it < 48; ++it) {
      float s = 0.f, c = 0.f;
#pragma unroll
      for (int kk = 0; kk < 32; ++kk)
        if (z[kk] > tau) { s += z[kk]; c += 1.f; }
#pragma unroll
      for (int o = 32; o; o >>= 1) { s += __shfl_xor(s, o); c += __shfl_xor(c, o); }
      if (c == cprev) break;
      tau = (s - 1.0f) / c; cprev = c;
    }
    float acc_o = 0.f;
#pragma unroll
    for (int kk = 0; kk < 32; ++kk) {
      float p = z[kk] - tau;
      unsigned long long m = __ballot(p > 0.f);
      while (m) {
        int src = __ffsll((long long)m) - 1;
        m &= m - 1;
        float pj = __shfl(p, src);
        int j = kk * 64 + src;
        acc_o += pj * (float)Vp[(size_t)j * 64 + lane];
      }
    }
    int rowg = (bh >> 3) * 2048 + n;
    AO[(size_t)rowg * 512 + (bh & 7) * 64 + lane] = (__bf16)acc_o;
  }
}

// ---------------- kernel 3: out = AO @ W_out + b_out.  128x128 tile, T14 pipeline ----
__global__ __launch_bounds__(256) void out_gemm(
    const __bf16* __restrict__ A, const __bf16* __restrict__ wot,
    const float* __restrict__ bias, float* __restrict__ out) {
  __shared__ __bf16 Asm[128 * 64];
  __shared__ __bf16 Bsm[128 * 64];
  int bid = blockIdx.x;
  int bn = bid & 3, bm = bid >> 2;          // 4 col-tiles x 32 row-tiles of 128
  int t = threadIdx.x, lane = t & 63, wid = t >> 6;
  int wy = wid >> 1, wx = wid & 1;
  int l15 = lane & 15, lg = lane >> 4;
  int sr = t >> 3, sc = t & 7;
  const __bf16* Ag = A   + (size_t)(bm * 128 + sr) * 512 + sc * 8;
  const __bf16* Bg = wot + (size_t)(bn * 128 + sr) * 512 + sc * 8;
  int swz = (sc * 16) ^ ((sr & 7) << 4);
  bf8 ra[4], rb[4];
#pragma unroll
  for (int j = 0; j < 4; ++j) {
    ra[j] = *(const bf8*)(Ag + (size_t)(j * 32) * 512);
    rb[j] = *(const bf8*)(Bg + (size_t)(j * 32) * 512);
  }
  f4 acc[4][4];
#pragma unroll
  for (int mt = 0; mt < 4; ++mt)
#pragma unroll
    for (int nt = 0; nt < 4; ++nt) acc[mt][nt] = (f4){0.f, 0.f, 0.f, 0.f};

  for (int ks = 0; ks < 8; ++ks) {
    __syncthreads();
#pragma unroll
    for (int j = 0; j < 4; ++j) {
      *(bf8*)((char*)Asm + (size_t)(j * 32 + sr) * 128 + swz) = ra[j];
      *(bf8*)((char*)Bsm + (size_t)(j * 32 + sr) * 128 + swz) = rb[j];
    }
    if (ks < 7) {
      const __bf16* Ag2 = Ag + (ks + 1) * 64;
      const __bf16* Bg2 = Bg + (ks + 1) * 64;
#pragma unroll
      for (int j = 0; j < 4; ++j) {
        ra[j] = *(const bf8*)(Ag2 + (size_t)(j * 32) * 512);
        rb[j] = *(const bf8*)(Bg2 + (size_t)(j * 32) * 512);
      }
    }
    __syncthreads();
#pragma unroll
    for (int kk = 0; kk < 2; ++kk) {
      bf8 af[4], bg[4];
#pragma unroll
      for (int mt = 0; mt < 4; ++mt) {
        int r = wy * 64 + mt * 16 + l15;
        af[mt] = *(const bf8*)((const char*)Asm + (size_t)r * 128 +
                               ((kk * 64 + lg * 16) ^ ((r & 7) << 4)));
      }
#pragma unroll
      for (int nt = 0; nt < 4; ++nt) {
        int r = wx * 64 + nt * 16 + l15;
        bg[nt] = *(const bf8*)((const char*)Bsm + (size_t)r * 128 +
                               ((kk * 64 + lg * 16) ^ ((r & 7) << 4)));
      }
#pragma unroll
      for (int mt = 0; mt < 4; ++mt)
#pragma unroll
        for (int nt = 0; nt < 4; ++nt)
          acc[mt][nt] = __builtin_amdgcn_mfma_f32_16x16x32_bf16(af[mt], bg[nt], acc[mt][nt], 0, 0, 0);
    }
  }
#pragma unroll
  for (int mt = 0; mt < 4; ++mt)
#pragma unroll
    for (int nt = 0; nt < 4; ++nt) {
      int col = bn * 128 + wx * 64 + nt * 16 + l15;
      float bv = bias[col];
#pragma unroll
      for (int i = 0; i < 4; ++i) {
        int row = bm * 128 + wy * 64 + mt * 16 + lg * 4 + i;
        out[(size_t)row * 512 + col] = acc[mt][nt][i] + bv;
      }
    }
}

extern "C" void kernel_launch(void* const* d_in, const int* in_sizes, int n_in,
                              void* d_out, int out_size, void* d_ws, size_t ws_size,
                              hipStream_t stream) {
  const float* x  = (const float*)d_in[0];
  const float* Wq = (const float*)d_in[1];
  const float* Wo = (const float*)d_in[2];
  const float* bo = (const float*)d_in[3];
  char* ws = (char*)d_ws;
  __bf16* xb  = (__bf16*)(ws + XB_OFF);
  __bf16* wqt = (__bf16*)(ws + WQT_OFF);
  __bf16* wot = (__bf16*)(ws + WOT_OFF);
  __bf16* Qh  = (__bf16*)(ws + Q_OFF);
  __bf16* Kh  = (__bf16*)(ws + K_OFF);
  __bf16* Vh  = (__bf16*)(ws + V_OFF);
  __bf16* AO  = (__bf16*)(ws + AO_OFF);
  unsigned* cd = (unsigned*)(ws + CAND_OFF);
  unsigned* ov = (unsigned*)(ws + OVF_OFF);

  prep_kernel<<<(ROWS * DIM) / 256, 256, 0, stream>>>(x, Wq, Wo, xb, wqt, wot, ov);
  qkv_gemm<<<32 * 12, 256, 0, stream>>>(xb, wqt, Qh, Kh, Vh);
  qk_gemm<<<4096, 256, 0, stream>>>(Qh, Kh, cd, ov);
  sparse_pv<<<4096, 512, 0, stream>>>(cd, Vh, AO);
  sparse_fb<<<512, 512, 0, stream>>>(Qh, Kh, Vh, AO, ov);
  out_gemm<<<128, 256, 0, stream>>>(AO, wot, bo, (float*)d_out);
}

// Round 23
// 188.264 us; speedup vs baseline: 7.3638x; 7.3638x over previous
//
#include <hip/hip_runtime.h>

typedef __bf16 bf8 __attribute__((ext_vector_type(8)));
typedef float f4 __attribute__((ext_vector_type(4)));
typedef unsigned int u4 __attribute__((ext_vector_type(4)));

// Problem constants (fixed by reference)
constexpr int BSZ = 2, NSEQ = 2048, DIM = 512, NH = 8, DH = 64, INNER = 512;
constexpr int ROWS = BSZ * NSEQ;          // 4096

// Workspace layout (bytes) — d_ws is >=268 MB (harness poison size)
constexpr size_t XB_OFF  = 0;                          // x cast bf16: 4 MB
constexpr size_t WQT_OFF = 4194304;                    // W_qkv^T bf16: 1.5 MB
constexpr size_t WOT_OFF = WQT_OFF + 1572864;          // W_out^T bf16: 0.5 MB
constexpr size_t Q_OFF   = WOT_OFF + 524288;           // Q/8 bf16 [16][2048][64]: 4 MB
constexpr size_t K_OFF   = Q_OFF + 4194304;            // K bf16: 4 MB
constexpr size_t V_OFF   = K_OFF + 4194304;            // V bf16: 4 MB
constexpr size_t AO_OFF  = V_OFF + 4194304;            // attn out bf16 [4096][512]: 4 MB
constexpr size_t CAND_OFF= AO_OFF + 4194304;           // cand u32 [32768][16][16]: 32 MB
constexpr size_t BM_OFF  = CAND_OFF + 33554432;        // bmax f32 [32768][16]: 2 MB
constexpr size_t OVB_OFF = BM_OFF + 2097152;           // per-block ovf u8 [32768][16]: 512 KB
constexpr size_t OVF_OFF = OVB_OFF + 524288;           // per-row ovf u32 [32768]: 128 KB
// total ~63 MB

// ---------------- prep: cast x to bf16; transpose+cast weights ----------------
__global__ __launch_bounds__(256) void prep_kernel(
    const float* __restrict__ x, const float* __restrict__ Wq, const float* __restrict__ Wo,
    __bf16* __restrict__ xb, __bf16* __restrict__ wqt, __bf16* __restrict__ wot) {
  int idx = blockIdx.x * 256 + threadIdx.x;
  if (idx < ROWS * DIM) xb[idx] = (__bf16)x[idx];
  if (idx < 3 * INNER * DIM) {            // wqt[n][k] = Wq[k][n]
    int n = idx >> 9, k = idx & 511;
    wqt[idx] = (__bf16)Wq[k * (3 * INNER) + n];
  }
  if (idx < INNER * DIM) {                // wot[n][k] = Wo[k][n]
    int n = idx >> 9, k = idx & 511;
    wot[idx] = (__bf16)Wo[k * DIM + n];
  }
}

// ---------------- kernel 1: qkv = x @ W_qkv -> Q/8,K,V.  128x128 tile, BK=64, ----
// T14 reg-staged LDS pipeline: issue loads for step k+1 before computing step k.
__global__ __launch_bounds__(256) void qkv_gemm(
    const __bf16* __restrict__ xb, const __bf16* __restrict__ wqt,
    __bf16* __restrict__ Qh, __bf16* __restrict__ Kh, __bf16* __restrict__ Vh) {
  __shared__ __bf16 Asm[128 * 64];          // byte = r*128 + (chbyte ^ ((r&7)<<4))
  __shared__ __bf16 Bsm[128 * 64];
  int bid = blockIdx.x;
  int bn = bid % 12, bm = bid / 12;         // 12 col-tiles x 32 row-tiles of 128
  int t = threadIdx.x, lane = t & 63, wid = t >> 6;
  int wy = wid >> 1, wx = wid & 1;
  int l15 = lane & 15, lg = lane >> 4;
  int sr = t >> 3, sc = t & 7;
  const __bf16* Ag = xb  + (size_t)(bm * 128 + sr) * 512 + sc * 8;
  const __bf16* Bg = wqt + (size_t)(bn * 128 + sr) * 512 + sc * 8;
  int swz = (sc * 16) ^ ((sr & 7) << 4);    // (j*32 preserves r&7)
  bf8 ra[4], rb[4];
#pragma unroll
  for (int j = 0; j < 4; ++j) {
    ra[j] = *(const bf8*)(Ag + (size_t)(j * 32) * 512);
    rb[j] = *(const bf8*)(Bg + (size_t)(j * 32) * 512);
  }
  f4 acc[4][4];
#pragma unroll
  for (int mt = 0; mt < 4; ++mt)
#pragma unroll
    for (int nt = 0; nt < 4; ++nt) acc[mt][nt] = (f4){0.f, 0.f, 0.f, 0.f};

  for (int ks = 0; ks < 8; ++ks) {
    __syncthreads();
#pragma unroll
    for (int j = 0; j < 4; ++j) {
      *(bf8*)((char*)Asm + (size_t)(j * 32 + sr) * 128 + swz) = ra[j];
      *(bf8*)((char*)Bsm + (size_t)(j * 32 + sr) * 128 + swz) = rb[j];
    }
    if (ks < 7) {
      const __bf16* Ag2 = Ag + (ks + 1) * 64;
      const __bf16* Bg2 = Bg + (ks + 1) * 64;
#pragma unroll
      for (int j = 0; j < 4; ++j) {
        ra[j] = *(const bf8*)(Ag2 + (size_t)(j * 32) * 512);
        rb[j] = *(const bf8*)(Bg2 + (size_t)(j * 32) * 512);
      }
    }
    __syncthreads();
#pragma unroll
    for (int kk = 0; kk < 2; ++kk) {
      bf8 af[4], bg[4];
#pragma unroll
      for (int mt = 0; mt < 4; ++mt) {
        int r = wy * 64 + mt * 16 + l15;
        af[mt] = *(const bf8*)((const char*)Asm + (size_t)r * 128 +
                               ((kk * 64 + lg * 16) ^ ((r & 7) << 4)));
      }
#pragma unroll
      for (int nt = 0; nt < 4; ++nt) {
        int r = wx * 64 + nt * 16 + l15;
        bg[nt] = *(const bf8*)((const char*)Bsm + (size_t)r * 128 +
                               ((kk * 64 + lg * 16) ^ ((r & 7) << 4)));
      }
#pragma unroll
      for (int mt = 0; mt < 4; ++mt)
#pragma unroll
        for (int nt = 0; nt < 4; ++nt)
          acc[mt][nt] = __builtin_amdgcn_mfma_f32_16x16x32_bf16(af[mt], bg[nt], acc[mt][nt], 0, 0, 0);
    }
  }
#pragma unroll
  for (int mt = 0; mt < 4; ++mt)
#pragma unroll
    for (int nt = 0; nt < 4; ++nt) {
      int col = bn * 128 + wx * 64 + nt * 16 + l15;
      int which = col >> 9;                  // 0=q 1=k 2=v
      int inner = col & 511;
      int h = inner >> 6, d = inner & 63;
      __bf16* dst = which == 0 ? Qh : (which == 1 ? Kh : Vh);
      float scale = which == 0 ? 0.125f : 1.0f;
#pragma unroll
      for (int i = 0; i < 4; ++i) {
        int row = bm * 128 + wy * 64 + mt * 16 + lg * 4 + i;
        int b = row >> 11, n = row & 2047;
        dst[(((size_t)(b * 8 + h)) * 2048 + n) * 64 + d] = (__bf16)(acc[mt][nt][i] * scale);
      }
    }
}

// ---------------- kernel 2a: QK^T -> candidate lists + bmax + per-block ovf ----
// Local extraction (thr = bmax_blk - 1.01, 16 slots); global safety handled in
// sparse_pv via Michelot-on-bmax: overflowed blocks with bmax <= tau_lb are
// provably irrelevant (their dropped values <= bmax <= tau*).
__global__ __launch_bounds__(256) void qk_gemm(
    const __bf16* __restrict__ Qh, const __bf16* __restrict__ Kh,
    unsigned* __restrict__ cand, float* __restrict__ bmax,
    unsigned char* __restrict__ ovb) {
  __shared__ char lds[16384];               // K-tile [128][64] bf16, swizzled
  int bid = blockIdx.x;
  int lin = (bid & 7) * 512 + (bid >> 3);   // bijective XCD swizzle (4096 % 8 == 0)
  int bh = lin >> 8;                        // head 0..15
  int rt = (lin >> 4) & 15;                 // q row-tile (128)
  int colt = lin & 15;                      // k col-tile (128)
  int t = threadIdx.x, lane = t & 63, wid = t >> 6;
  int l15 = lane & 15, lg = lane >> 4;

  {
    int sr = t >> 3, sc = t & 7;            // 32 rows/pass, full 128B rows coalesced
    const __bf16* Kg = Kh + ((size_t)bh * 2048 + colt * 128 + sr) * 64 + sc * 8;
    bf8 k0 = *(const bf8*)(Kg);
    bf8 k1 = *(const bf8*)(Kg + 32 * 64);
    bf8 k2 = *(const bf8*)(Kg + 64 * 64);
    bf8 k3 = *(const bf8*)(Kg + 96 * 64);
    int swz = (sc * 16) ^ ((sr & 7) << 4);
    *(bf8*)(lds + (size_t)sr * 128 + swz) = k0;
    *(bf8*)(lds + (size_t)(sr + 32) * 128 + swz) = k1;
    *(bf8*)(lds + (size_t)(sr + 64) * 128 + swz) = k2;
    *(bf8*)(lds + (size_t)(sr + 96) * 128 + swz) = k3;
  }
  const __bf16* Qp = Qh + ((size_t)bh * 2048 + rt * 128 + wid * 32) * 64;
  bf8 aA0 = *(const bf8*)(Qp + l15 * 64 + lg * 8);
  bf8 aA1 = *(const bf8*)(Qp + l15 * 64 + 32 + lg * 8);
  bf8 aB0 = *(const bf8*)(Qp + (16 + l15) * 64 + lg * 8);
  bf8 aB1 = *(const bf8*)(Qp + (16 + l15) * 64 + 32 + lg * 8);
  __syncthreads();                          // K-tile ready

  f4 acc[2][8];
#pragma unroll
  for (int s = 0; s < 2; ++s)
#pragma unroll
    for (int j = 0; j < 8; ++j) acc[s][j] = (f4){0.f, 0.f, 0.f, 0.f};
#pragma unroll
  for (int ctj = 0; ctj < 8; ++ctj) {
    int r = ctj * 16 + l15;
    const char* kb = lds + (size_t)r * 128;
    int sw = (r & 7) << 4;
    bf8 b0 = *(const bf8*)(kb + ((lg * 16) ^ sw));
    bf8 b1 = *(const bf8*)(kb + ((64 + lg * 16) ^ sw));
    acc[0][ctj] = __builtin_amdgcn_mfma_f32_16x16x32_bf16(aA0, b0, acc[0][ctj], 0, 0, 0);
    acc[0][ctj] = __builtin_amdgcn_mfma_f32_16x16x32_bf16(aA1, b1, acc[0][ctj], 0, 0, 0);
    acc[1][ctj] = __builtin_amdgcn_mfma_f32_16x16x32_bf16(aB0, b0, acc[1][ctj], 0, 0, 0);
    acc[1][ctj] = __builtin_amdgcn_mfma_f32_16x16x32_bf16(aB1, b1, acc[1][ctj], 0, 0, 0);
  }
  unsigned lm15 = (1u << l15) - 1;
#pragma unroll
  for (int s = 0; s < 2; ++s)
#pragma unroll
    for (int i = 0; i < 4; ++i) {
      float rm = acc[s][0][i];
#pragma unroll
      for (int ctj = 1; ctj < 8; ++ctj) rm = fmaxf(rm, acc[s][ctj][i]);
#pragma unroll
      for (int o = 1; o < 16; o <<= 1) rm = fmaxf(rm, __shfl_xor(rm, o));
      float thr = rm - 1.01f;
      int rowg = bh * 2048 + rt * 128 + wid * 32 + s * 16 + lg * 4 + i;
      unsigned* grp = cand + ((size_t)rowg << 8) + colt * 16;
      int base = 0;
#pragma unroll
      for (int ctj = 0; ctj < 8; ++ctj) {
        float zf = acc[s][ctj][i];
        bool c = zf > thr;
        unsigned long long b = __ballot(c);
        unsigned seg = (unsigned)((b >> (lg * 16)) & 0xFFFFu);
        if (c) {
          int slot = base + __popc(seg & lm15);
          if (slot < 16) {
            _Float16 hv = (_Float16)zf;
            unsigned short hb = __builtin_bit_cast(unsigned short, hv);
            grp[slot] = ((unsigned)hb << 16) | (unsigned)(colt * 128 + ctj * 16 + l15);
          }
        }
        base += __popc(seg);
      }
      if (l15 >= base && l15 < 16) grp[l15] = 0xFC000000u;   // -inf pad
      if (l15 == 0) {
        bmax[(size_t)rowg * 16 + colt] = rm;
        ovb[(size_t)rowg * 16 + colt] = (base > 16) ? 1 : 0; // unconditional write
      }
    }
}

// ---------------- kernel 2b: sparsemax + sparse PV from candidate lists ----
// Global tau_lb via Michelot on 16 block maxima; overflowed blocks with
// f16(bmax) <= tau_lb-0.01 are provably irrelevant; else exact fallback.
__global__ __launch_bounds__(512, 8) void sparse_pv(
    const unsigned* __restrict__ cand, const float* __restrict__ bmax,
    const unsigned char* __restrict__ ovb, const __bf16* __restrict__ Vh,
    __bf16* __restrict__ AO, unsigned* __restrict__ ovf) {
  int lane = threadIdx.x & 63, wid = threadIdx.x >> 6;   // 8 waves
  int rowid = blockIdx.x * 8 + wid;         // 0..32767
  int bh = rowid >> 11, n = rowid & 2047;
  const unsigned* cr = cand + ((size_t)rowid << 8);
  const float* bmr = bmax + (size_t)rowid * 16;
  const unsigned* ovr = (const unsigned*)(ovb + (size_t)rowid * 16);
  const __bf16* Vp = Vh + (size_t)bh * 2048 * 64;

  float bmv[16];
  *(f4*)&bmv[0]  = *(const f4*)&bmr[0];
  *(f4*)&bmv[4]  = *(const f4*)&bmr[4];
  *(f4*)&bmv[8]  = *(const f4*)&bmr[8];
  *(f4*)&bmv[12] = *(const f4*)&bmr[12];
  unsigned ov0 = ovr[0], ov1 = ovr[1], ov2 = ovr[2], ov3 = ovr[3];
  float gmax = bmv[0];
#pragma unroll
  for (int ct = 1; ct < 16; ++ct) gmax = fmaxf(gmax, bmv[ct]);
  // Michelot on 16 block maxima (real row elements) -> lower bound of tau*
  float tlb = gmax - 1.0f;
#pragma unroll
  for (int it = 0; it < 3; ++it) {
    float s = 0.f, c = 0.f;
#pragma unroll
    for (int ct = 0; ct < 16; ++ct) {
      float v = bmv[ct];
      if (v > tlb) { s += v; c += 1.f; }
    }
    tlb = (s - 1.0f) / c;
  }
  float tsafe = tlb - 0.01f;                // f16-rounding margin
  // overflowed block is dangerous only if its max can exceed tau*
  bool needs_fb = false;
#pragma unroll
  for (int ct = 0; ct < 16; ++ct) {
    unsigned byte = (ct < 4 ? ov0 : (ct < 8 ? ov1 : (ct < 12 ? ov2 : ov3)));
    byte = (byte >> ((ct & 3) * 8)) & 0xFF;
    if (byte && bmv[ct] > tsafe) needs_fb = true;
  }
  if (lane == 0) ovf[rowid] = needs_fb ? 1u : 0u;   // every row written: no prep zero
  if (needs_fb) return;                     // sparse_fb recomputes this row exactly

  u4 w = *(const u4*)(cr + lane * 4);       // 4 packed candidates per lane
  float v0, v1, v2, v3;
  {
    unsigned short h0 = (unsigned short)(w[0] >> 16);
    unsigned short h1 = (unsigned short)(w[1] >> 16);
    unsigned short h2v = (unsigned short)(w[2] >> 16);
    unsigned short h3 = (unsigned short)(w[3] >> 16);
    v0 = (float)__builtin_bit_cast(_Float16, h0);
    v1 = (float)__builtin_bit_cast(_Float16, h1);
    v2 = (float)__builtin_bit_cast(_Float16, h2v);
    v3 = (float)__builtin_bit_cast(_Float16, h3);
  }
  int j0 = w[0] & 2047, j1 = w[1] & 2047, j2 = w[2] & 2047, j3 = w[3] & 2047;

  float mx = fmaxf(fmaxf(v0, v1), fmaxf(v2, v3));
#pragma unroll
  for (int o = 32; o; o >>= 1) mx = fmaxf(mx, __shfl_xor(mx, o));

  float tau = fmaxf(mx - 1.0f, tsafe), cprev = -1.0f;
  for (int it = 0; it < 16; ++it) {
    float s = 0.f, c = 0.f;
    if (v0 > tau) { s += v0; c += 1.f; }
    if (v1 > tau) { s += v1; c += 1.f; }
    if (v2 > tau) { s += v2; c += 1.f; }
    if (v3 > tau) { s += v3; c += 1.f; }
#pragma unroll
    for (int o = 32; o; o >>= 1) { s += __shfl_xor(s, o); c += __shfl_xor(c, o); }
    if (c == cprev) break;
    tau = (s - 1.0f) / c; cprev = c;
  }
  float acc_o = 0.f;
  float p0 = v0 - tau, p1 = v1 - tau, p2 = v2 - tau, p3 = v3 - tau;
#pragma unroll
  for (int q = 0; q < 4; ++q) {
    float p = q == 0 ? p0 : (q == 1 ? p1 : (q == 2 ? p2 : p3));
    int jj = q == 0 ? j0 : (q == 1 ? j1 : (q == 2 ? j2 : j3));
    unsigned long long m = __ballot(p > 0.f);
    while (m) {
      int src = __ffsll((long long)m) - 1;
      m &= m - 1;
      float pj = __shfl(p, src);
      int j = __shfl(jj, src);
      acc_o += pj * (float)Vp[(size_t)j * 64 + lane];
    }
  }
  int rowg = (bh >> 3) * 2048 + n;          // [B][N] row
  AO[(size_t)rowg * 512 + (bh & 7) * 64 + lane] = (__bf16)acc_o;
}

// ---------------- kernel 2c: exact fallback for flagged rows (rare) ----------------
__global__ __launch_bounds__(512) void sparse_fb(
    const __bf16* __restrict__ Qh, const __bf16* __restrict__ Kh,
    const __bf16* __restrict__ Vh, __bf16* __restrict__ AO,
    const unsigned* __restrict__ ovf) {
  int lane = threadIdx.x & 63, wid = threadIdx.x >> 6;
  for (int rowid = blockIdx.x * 8 + wid; rowid < 32768; rowid += gridDim.x * 8) {
    if (ovf[rowid] == 0) continue;
    int bh = rowid >> 11, n = rowid & 2047;
    const __bf16* qp = Qh + ((size_t)bh * 2048 + n) * 64;
    bf8 qv[8];
#pragma unroll
    for (int j = 0; j < 8; ++j) qv[j] = *(const bf8*)(qp + j * 8);
    const __bf16* Kp = Kh + (size_t)bh * 2048 * 64;
    const __bf16* Vp = Vh + (size_t)bh * 2048 * 64;
    float z[32];
    for (int kk = 0; kk < 32; ++kk) {
      const __bf16* kr = Kp + (size_t)(kk * 64 + lane) * 64;
      float d = 0.f;
#pragma unroll
      for (int j = 0; j < 8; ++j) {
        bf8 kv = *(const bf8*)(kr + j * 8);
#pragma unroll
        for (int e = 0; e < 8; ++e) d += (float)qv[j][e] * (float)kv[e];
      }
      z[kk] = d;
    }
    float mx = z[0];
#pragma unroll
    for (int kk = 1; kk < 32; ++kk) mx = fmaxf(mx, z[kk]);
#pragma unroll
    for (int o = 32; o; o >>= 1) mx = fmaxf(mx, __shfl_xor(mx, o));
    float tau = mx - 1.0f, cprev = -1.0f;
    for (int it = 0; it < 48; ++it) {
      float s = 0.f, c = 0.f;
#pragma unroll
      for (int kk = 0; kk < 32; ++kk)
        if (z[kk] > tau) { s += z[kk]; c += 1.f; }
#pragma unroll
      for (int o = 32; o; o >>= 1) { s += __shfl_xor(s, o); c += __shfl_xor(c, o); }
      if (c == cprev) break;
      tau = (s - 1.0f) / c; cprev = c;
    }
    float acc_o = 0.f;
#pragma unroll
    for (int kk = 0; kk < 32; ++kk) {
      float p = z[kk] - tau;
      unsigned long long m = __ballot(p > 0.f);
      while (m) {
        int src = __ffsll((long long)m) - 1;
        m &= m - 1;
        float pj = __shfl(p, src);
        int j = kk * 64 + src;
        acc_o += pj * (float)Vp[(size_t)j * 64 + lane];
      }
    }
    int rowg = (bh >> 3) * 2048 + n;
    AO[(size_t)rowg * 512 + (bh & 7) * 64 + lane] = (__bf16)acc_o;
  }
}

// ---------------- kernel 3: out = AO @ W_out + b_out.  128x128 tile, T14 pipeline ----
__global__ __launch_bounds__(256) void out_gemm(
    const __bf16* __restrict__ A, const __bf16* __restrict__ wot,
    const float* __restrict__ bias, float* __restrict__ out) {
  __shared__ __bf16 Asm[128 * 64];
  __shared__ __bf16 Bsm[128 * 64];
  int bid = blockIdx.x;
  int bn = bid & 3, bm = bid >> 2;          // 4 col-tiles x 32 row-tiles of 128
  int t = threadIdx.x, lane = t & 63, wid = t >> 6;
  int wy = wid >> 1, wx = wid & 1;
  int l15 = lane & 15, lg = lane >> 4;
  int sr = t >> 3, sc = t & 7;
  const __bf16* Ag = A   + (size_t)(bm * 128 + sr) * 512 + sc * 8;
  const __bf16* Bg = wot + (size_t)(bn * 128 + sr) * 512 + sc * 8;
  int swz = (sc * 16) ^ ((sr & 7) << 4);
  bf8 ra[4], rb[4];
#pragma unroll
  for (int j = 0; j < 4; ++j) {
    ra[j] = *(const bf8*)(Ag + (size_t)(j * 32) * 512);
    rb[j] = *(const bf8*)(Bg + (size_t)(j * 32) * 512);
  }
  f4 acc[4][4];
#pragma unroll
  for (int mt = 0; mt < 4; ++mt)
#pragma unroll
    for (int nt = 0; nt < 4; ++nt) acc[mt][nt] = (f4){0.f, 0.f, 0.f, 0.f};

  for (int ks = 0; ks < 8; ++ks) {
    __syncthreads();
#pragma unroll
    for (int j = 0; j < 4; ++j) {
      *(bf8*)((char*)Asm + (size_t)(j * 32 + sr) * 128 + swz) = ra[j];
      *(bf8*)((char*)Bsm + (size_t)(j * 32 + sr) * 128 + swz) = rb[j];
    }
    if (ks < 7) {
      const __bf16* Ag2 = Ag + (ks + 1) * 64;
      const __bf16* Bg2 = Bg + (ks + 1) * 64;
#pragma unroll
      for (int j = 0; j < 4; ++j) {
        ra[j] = *(const bf8*)(Ag2 + (size_t)(j * 32) * 512);
        rb[j] = *(const bf8*)(Bg2 + (size_t)(j * 32) * 512);
      }
    }
    __syncthreads();
#pragma unroll
    for (int kk = 0; kk < 2; ++kk) {
      bf8 af[4], bg[4];
#pragma unroll
      for (int mt = 0; mt < 4; ++mt) {
        int r = wy * 64 + mt * 16 + l15;
        af[mt] = *(const bf8*)((const char*)Asm + (size_t)r * 128 +
                               ((kk * 64 + lg * 16) ^ ((r & 7) << 4)));
      }
#pragma unroll
      for (int nt = 0; nt < 4; ++nt) {
        int r = wx * 64 + nt * 16 + l15;
        bg[nt] = *(const bf8*)((const char*)Bsm + (size_t)r * 128 +
                               ((kk * 64 + lg * 16) ^ ((r & 7) << 4)));
      }
#pragma unroll
      for (int mt = 0; mt < 4; ++mt)
#pragma unroll
        for (int nt = 0; nt < 4; ++nt)
          acc[mt][nt] = __builtin_amdgcn_mfma_f32_16x16x32_bf16(af[mt], bg[nt], acc[mt][nt], 0, 0, 0);
    }
  }
#pragma unroll
  for (int mt = 0; mt < 4; ++mt)
#pragma unroll
    for (int nt = 0; nt < 4; ++nt) {
      int col = bn * 128 + wx * 64 + nt * 16 + l15;
      float bv = bias[col];
#pragma unroll
      for (int i = 0; i < 4; ++i) {
        int row = bm * 128 + wy * 64 + mt * 16 + lg * 4 + i;
        out[(size_t)row * 512 + col] = acc[mt][nt][i] + bv;
      }
    }
}

extern "C" void kernel_launch(void* const* d_in, const int* in_sizes, int n_in,
                              void* d_out, int out_size, void* d_ws, size_t ws_size,
                              hipStream_t stream) {
  const float* x  = (const float*)d_in[0];
  const float* Wq = (const float*)d_in[1];
  const float* Wo = (const float*)d_in[2];
  const float* bo = (const float*)d_in[3];
  char* ws = (char*)d_ws;
  __bf16* xb  = (__bf16*)(ws + XB_OFF);
  __bf16* wqt = (__bf16*)(ws + WQT_OFF);
  __bf16* wot = (__bf16*)(ws + WOT_OFF);
  __bf16* Qh  = (__bf16*)(ws + Q_OFF);
  __bf16* Kh  = (__bf16*)(ws + K_OFF);
  __bf16* Vh  = (__bf16*)(ws + V_OFF);
  __bf16* AO  = (__bf16*)(ws + AO_OFF);
  unsigned* cd = (unsigned*)(ws + CAND_OFF);
  float* bm = (float*)(ws + BM_OFF);
  unsigned char* ob = (unsigned char*)(ws + OVB_OFF);
  unsigned* ov = (unsigned*)(ws + OVF_OFF);

  prep_kernel<<<(ROWS * DIM) / 256, 256, 0, stream>>>(x, Wq, Wo, xb, wqt, wot);
  qkv_gemm<<<32 * 12, 256, 0, stream>>>(xb, wqt, Qh, Kh, Vh);
  qk_gemm<<<4096, 256, 0, stream>>>(Qh, Kh, cd, bm, ob);
  sparse_pv<<<4096, 512, 0, stream>>>(cd, bm, ob, Vh, AO, ov);
  sparse_fb<<<512, 512, 0, stream>>>(Qh, Kh, Vh, AO, ov);
  out_gemm<<<128, 256, 0, stream>>>(AO, wot, bo, (float*)d_out);
}

// Round 24
// 154.038 us; speedup vs baseline: 9.0000x; 1.2222x over previous
//
#include <hip/hip_runtime.h>

typedef __bf16 bf8 __attribute__((ext_vector_type(8)));
typedef float f4 __attribute__((ext_vector_type(4)));
typedef unsigned int u4 __attribute__((ext_vector_type(4)));

// Problem constants (fixed by reference)
constexpr int BSZ = 2, NSEQ = 2048, DIM = 512, NH = 8, DH = 64, INNER = 512;
constexpr int ROWS = BSZ * NSEQ;          // 4096

// Workspace layout (bytes) — d_ws is >=268 MB (harness poison size)
constexpr size_t XB_OFF  = 0;                          // x cast bf16: 4 MB
constexpr size_t WQT_OFF = 4194304;                    // W_qkv^T bf16: 1.5 MB
constexpr size_t WOT_OFF = WQT_OFF + 1572864;          // W_out^T bf16: 0.5 MB
constexpr size_t Q_OFF   = WOT_OFF + 524288;           // Q/8 bf16 [16][2048][64]: 4 MB
constexpr size_t K_OFF   = Q_OFF + 4194304;            // K bf16: 4 MB
constexpr size_t V_OFF   = K_OFF + 4194304;            // V bf16: 4 MB
constexpr size_t AO_OFF  = V_OFF + 4194304;            // attn out bf16 [4096][512]: 4 MB
constexpr size_t CAND_OFF= AO_OFF + 4194304;           // cand u32 [32768][16][16]: 32 MB
constexpr size_t BM_OFF  = CAND_OFF + 33554432;        // bmax f32 [32768][16]: 2 MB
constexpr size_t OVB_OFF = BM_OFF + 2097152;           // per-block ovf u8 [32768][16]: 512 KB
constexpr size_t OVF_OFF = OVB_OFF + 524288;           // per-row ovf u32 [32768]: 128 KB
// total ~63 MB

// ---------------- prep: cast x to bf16; transpose+cast weights ----------------
__global__ __launch_bounds__(256) void prep_kernel(
    const float* __restrict__ x, const float* __restrict__ Wq, const float* __restrict__ Wo,
    __bf16* __restrict__ xb, __bf16* __restrict__ wqt, __bf16* __restrict__ wot) {
  int idx = blockIdx.x * 256 + threadIdx.x;
  if (idx < ROWS * DIM) xb[idx] = (__bf16)x[idx];
  if (idx < 3 * INNER * DIM) {            // wqt[n][k] = Wq[k][n]
    int n = idx >> 9, k = idx & 511;
    wqt[idx] = (__bf16)Wq[k * (3 * INNER) + n];
  }
  if (idx < INNER * DIM) {                // wot[n][k] = Wo[k][n]
    int n = idx >> 9, k = idx & 511;
    wot[idx] = (__bf16)Wo[k * DIM + n];
  }
}

// ---------------- kernel 1: qkv = x @ W_qkv -> Q/8,K,V.  128x128 tile, BK=64, ----
// T14 reg-staged LDS pipeline: issue loads for step k+1 before computing step k.
__global__ __launch_bounds__(256) void qkv_gemm(
    const __bf16* __restrict__ xb, const __bf16* __restrict__ wqt,
    __bf16* __restrict__ Qh, __bf16* __restrict__ Kh, __bf16* __restrict__ Vh) {
  __shared__ __bf16 Asm[128 * 64];          // byte = r*128 + (chbyte ^ ((r&7)<<4))
  __shared__ __bf16 Bsm[128 * 64];
  int bid = blockIdx.x;
  int bn = bid % 12, bm = bid / 12;         // 12 col-tiles x 32 row-tiles of 128
  int t = threadIdx.x, lane = t & 63, wid = t >> 6;
  int wy = wid >> 1, wx = wid & 1;
  int l15 = lane & 15, lg = lane >> 4;
  int sr = t >> 3, sc = t & 7;
  const __bf16* Ag = xb  + (size_t)(bm * 128 + sr) * 512 + sc * 8;
  const __bf16* Bg = wqt + (size_t)(bn * 128 + sr) * 512 + sc * 8;
  int swz = (sc * 16) ^ ((sr & 7) << 4);    // (j*32 preserves r&7)
  bf8 ra[4], rb[4];
#pragma unroll
  for (int j = 0; j < 4; ++j) {
    ra[j] = *(const bf8*)(Ag + (size_t)(j * 32) * 512);
    rb[j] = *(const bf8*)(Bg + (size_t)(j * 32) * 512);
  }
  f4 acc[4][4];
#pragma unroll
  for (int mt = 0; mt < 4; ++mt)
#pragma unroll
    for (int nt = 0; nt < 4; ++nt) acc[mt][nt] = (f4){0.f, 0.f, 0.f, 0.f};

  for (int ks = 0; ks < 8; ++ks) {
    __syncthreads();
#pragma unroll
    for (int j = 0; j < 4; ++j) {
      *(bf8*)((char*)Asm + (size_t)(j * 32 + sr) * 128 + swz) = ra[j];
      *(bf8*)((char*)Bsm + (size_t)(j * 32 + sr) * 128 + swz) = rb[j];
    }
    if (ks < 7) {
      const __bf16* Ag2 = Ag + (ks + 1) * 64;
      const __bf16* Bg2 = Bg + (ks + 1) * 64;
#pragma unroll
      for (int j = 0; j < 4; ++j) {
        ra[j] = *(const bf8*)(Ag2 + (size_t)(j * 32) * 512);
        rb[j] = *(const bf8*)(Bg2 + (size_t)(j * 32) * 512);
      }
    }
    __syncthreads();
#pragma unroll
    for (int kk = 0; kk < 2; ++kk) {
      bf8 af[4], bg[4];
#pragma unroll
      for (int mt = 0; mt < 4; ++mt) {
        int r = wy * 64 + mt * 16 + l15;
        af[mt] = *(const bf8*)((const char*)Asm + (size_t)r * 128 +
                               ((kk * 64 + lg * 16) ^ ((r & 7) << 4)));
      }
#pragma unroll
      for (int nt = 0; nt < 4; ++nt) {
        int r = wx * 64 + nt * 16 + l15;
        bg[nt] = *(const bf8*)((const char*)Bsm + (size_t)r * 128 +
                               ((kk * 64 + lg * 16) ^ ((r & 7) << 4)));
      }
#pragma unroll
      for (int mt = 0; mt < 4; ++mt)
#pragma unroll
        for (int nt = 0; nt < 4; ++nt)
          acc[mt][nt] = __builtin_amdgcn_mfma_f32_16x16x32_bf16(af[mt], bg[nt], acc[mt][nt], 0, 0, 0);
    }
  }
#pragma unroll
  for (int mt = 0; mt < 4; ++mt)
#pragma unroll
    for (int nt = 0; nt < 4; ++nt) {
      int col = bn * 128 + wx * 64 + nt * 16 + l15;
      int which = col >> 9;                  // 0=q 1=k 2=v
      int inner = col & 511;
      int h = inner >> 6, d = inner & 63;
      __bf16* dst = which == 0 ? Qh : (which == 1 ? Kh : Vh);
      float scale = which == 0 ? 0.125f : 1.0f;
#pragma unroll
      for (int i = 0; i < 4; ++i) {
        int row = bm * 128 + wy * 64 + mt * 16 + lg * 4 + i;
        int b = row >> 11, n = row & 2047;
        dst[(((size_t)(b * 8 + h)) * 2048 + n) * 64 + d] = (__bf16)(acc[mt][nt][i] * scale);
      }
    }
}

// ---------------- kernel 2a: QK^T -> candidate lists + bmax + per-block ovf ----
// Local extraction (thr = bmax_blk - 1.01, 16 slots); global safety handled in
// sparse_pv via Michelot-on-bmax: overflowed blocks with bmax <= tau_lb are
// provably irrelevant (their dropped values <= bmax <= tau*).
__global__ __launch_bounds__(256) void qk_gemm(
    const __bf16* __restrict__ Qh, const __bf16* __restrict__ Kh,
    unsigned* __restrict__ cand, float* __restrict__ bmax,
    unsigned char* __restrict__ ovb) {
  __shared__ char lds[16384];               // K-tile [128][64] bf16, swizzled
  int bid = blockIdx.x;
  int lin = (bid & 7) * 512 + (bid >> 3);   // bijective XCD swizzle (4096 % 8 == 0)
  int bh = lin >> 8;                        // head 0..15
  int rt = (lin >> 4) & 15;                 // q row-tile (128)
  int colt = lin & 15;                      // k col-tile (128)
  int t = threadIdx.x, lane = t & 63, wid = t >> 6;
  int l15 = lane & 15, lg = lane >> 4;

  {
    int sr = t >> 3, sc = t & 7;            // 32 rows/pass, full 128B rows coalesced
    const __bf16* Kg = Kh + ((size_t)bh * 2048 + colt * 128 + sr) * 64 + sc * 8;
    bf8 k0 = *(const bf8*)(Kg);
    bf8 k1 = *(const bf8*)(Kg + 32 * 64);
    bf8 k2 = *(const bf8*)(Kg + 64 * 64);
    bf8 k3 = *(const bf8*)(Kg + 96 * 64);
    int swz = (sc * 16) ^ ((sr & 7) << 4);
    *(bf8*)(lds + (size_t)sr * 128 + swz) = k0;
    *(bf8*)(lds + (size_t)(sr + 32) * 128 + swz) = k1;
    *(bf8*)(lds + (size_t)(sr + 64) * 128 + swz) = k2;
    *(bf8*)(lds + (size_t)(sr + 96) * 128 + swz) = k3;
  }
  const __bf16* Qp = Qh + ((size_t)bh * 2048 + rt * 128 + wid * 32) * 64;
  bf8 aA0 = *(const bf8*)(Qp + l15 * 64 + lg * 8);
  bf8 aA1 = *(const bf8*)(Qp + l15 * 64 + 32 + lg * 8);
  bf8 aB0 = *(const bf8*)(Qp + (16 + l15) * 64 + lg * 8);
  bf8 aB1 = *(const bf8*)(Qp + (16 + l15) * 64 + 32 + lg * 8);
  __syncthreads();                          // K-tile ready

  f4 acc[2][8];
#pragma unroll
  for (int s = 0; s < 2; ++s)
#pragma unroll
    for (int j = 0; j < 8; ++j) acc[s][j] = (f4){0.f, 0.f, 0.f, 0.f};
#pragma unroll
  for (int ctj = 0; ctj < 8; ++ctj) {
    int r = ctj * 16 + l15;
    const char* kb = lds + (size_t)r * 128;
    int sw = (r & 7) << 4;
    bf8 b0 = *(const bf8*)(kb + ((lg * 16) ^ sw));
    bf8 b1 = *(const bf8*)(kb + ((64 + lg * 16) ^ sw));
    acc[0][ctj] = __builtin_amdgcn_mfma_f32_16x16x32_bf16(aA0, b0, acc[0][ctj], 0, 0, 0);
    acc[0][ctj] = __builtin_amdgcn_mfma_f32_16x16x32_bf16(aA1, b1, acc[0][ctj], 0, 0, 0);
    acc[1][ctj] = __builtin_amdgcn_mfma_f32_16x16x32_bf16(aB0, b0, acc[1][ctj], 0, 0, 0);
    acc[1][ctj] = __builtin_amdgcn_mfma_f32_16x16x32_bf16(aB1, b1, acc[1][ctj], 0, 0, 0);
  }
  unsigned lm15 = (1u << l15) - 1;
#pragma unroll
  for (int s = 0; s < 2; ++s)
#pragma unroll
    for (int i = 0; i < 4; ++i) {
      float rm = acc[s][0][i];
#pragma unroll
      for (int ctj = 1; ctj < 8; ++ctj) rm = fmaxf(rm, acc[s][ctj][i]);
#pragma unroll
      for (int o = 1; o < 16; o <<= 1) rm = fmaxf(rm, __shfl_xor(rm, o));
      float thr = rm - 1.01f;
      int rowg = bh * 2048 + rt * 128 + wid * 32 + s * 16 + lg * 4 + i;
      unsigned* grp = cand + ((size_t)rowg << 8) + colt * 16;
      int base = 0;
#pragma unroll
      for (int ctj = 0; ctj < 8; ++ctj) {
        float zf = acc[s][ctj][i];
        bool c = zf > thr;
        unsigned long long b = __ballot(c);
        unsigned seg = (unsigned)((b >> (lg * 16)) & 0xFFFFu);
        if (c) {
          int slot = base + __popc(seg & lm15);
          if (slot < 16) {
            _Float16 hv = (_Float16)zf;
            unsigned short hb = __builtin_bit_cast(unsigned short, hv);
            grp[slot] = ((unsigned)hb << 16) | (unsigned)(colt * 128 + ctj * 16 + l15);
          }
        }
        base += __popc(seg);
      }
      if (l15 >= base && l15 < 16) grp[l15] = 0xFC000000u;   // -inf pad
      if (l15 == 0) {
        bmax[(size_t)rowg * 16 + colt] = rm;
        ovb[(size_t)rowg * 16 + colt] = (base > 16) ? 1 : 0; // unconditional write
      }
    }
}

// ---------------- kernel 2b: sparsemax + sparse PV from candidate lists ----
// Global tau_lb via Michelot on 16 block maxima; overflowed blocks with
// f16(bmax) <= tau_lb-0.01 are provably irrelevant; else exact fallback.
__global__ __launch_bounds__(512, 8) void sparse_pv(
    const unsigned* __restrict__ cand, const float* __restrict__ bmax,
    const unsigned char* __restrict__ ovb, const __bf16* __restrict__ Vh,
    __bf16* __restrict__ AO, unsigned* __restrict__ ovf) {
  int lane = threadIdx.x & 63, wid = threadIdx.x >> 6;   // 8 waves
  int rowid = blockIdx.x * 8 + wid;         // 0..32767
  int bh = rowid >> 11, n = rowid & 2047;
  const unsigned* cr = cand + ((size_t)rowid << 8);
  const float* bmr = bmax + (size_t)rowid * 16;
  const unsigned* ovr = (const unsigned*)(ovb + (size_t)rowid * 16);
  const __bf16* Vp = Vh + (size_t)bh * 2048 * 64;

  float bmv[16];
  *(f4*)&bmv[0]  = *(const f4*)&bmr[0];
  *(f4*)&bmv[4]  = *(const f4*)&bmr[4];
  *(f4*)&bmv[8]  = *(const f4*)&bmr[8];
  *(f4*)&bmv[12] = *(const f4*)&bmr[12];
  unsigned ov0 = ovr[0], ov1 = ovr[1], ov2 = ovr[2], ov3 = ovr[3];
  float gmax = bmv[0];
#pragma unroll
  for (int ct = 1; ct < 16; ++ct) gmax = fmaxf(gmax, bmv[ct]);
  // Michelot on 16 block maxima (real row elements) -> lower bound of tau*
  float tlb = gmax - 1.0f;
#pragma unroll
  for (int it = 0; it < 3; ++it) {
    float s = 0.f, c = 0.f;
#pragma unroll
    for (int ct = 0; ct < 16; ++ct) {
      float v = bmv[ct];
      if (v > tlb) { s += v; c += 1.f; }
    }
    tlb = (s - 1.0f) / c;
  }
  float tsafe = tlb - 0.01f;                // f16-rounding margin
  // overflowed block is dangerous only if its max can exceed tau*
  bool needs_fb = false;
#pragma unroll
  for (int ct = 0; ct < 16; ++ct) {
    unsigned byte = (ct < 4 ? ov0 : (ct < 8 ? ov1 : (ct < 12 ? ov2 : ov3)));
    byte = (byte >> ((ct & 3) * 8)) & 0xFF;
    if (byte && bmv[ct] > tsafe) needs_fb = true;
  }
  if (lane == 0) ovf[rowid] = needs_fb ? 1u : 0u;   // every row written: no prep zero
  if (needs_fb) return;                     // sparse_fb recomputes this row exactly

  u4 w = *(const u4*)(cr + lane * 4);       // 4 packed candidates per lane
  float v0, v1, v2, v3;
  {
    unsigned short h0 = (unsigned short)(w[0] >> 16);
    unsigned short h1 = (unsigned short)(w[1] >> 16);
    unsigned short h2v = (unsigned short)(w[2] >> 16);
    unsigned short h3 = (unsigned short)(w[3] >> 16);
    v0 = (float)__builtin_bit_cast(_Float16, h0);
    v1 = (float)__builtin_bit_cast(_Float16, h1);
    v2 = (float)__builtin_bit_cast(_Float16, h2v);
    v3 = (float)__builtin_bit_cast(_Float16, h3);
  }
  int j0 = w[0] & 2047, j1 = w[1] & 2047, j2 = w[2] & 2047, j3 = w[3] & 2047;

  float mx = fmaxf(fmaxf(v0, v1), fmaxf(v2, v3));
#pragma unroll
  for (int o = 32; o; o >>= 1) mx = fmaxf(mx, __shfl_xor(mx, o));

  float tau = fmaxf(mx - 1.0f, tsafe), cprev = -1.0f;
  for (int it = 0; it < 16; ++it) {
    float s = 0.f, c = 0.f;
    if (v0 > tau) { s += v0; c += 1.f; }
    if (v1 > tau) { s += v1; c += 1.f; }
    if (v2 > tau) { s += v2; c += 1.f; }
    if (v3 > tau) { s += v3; c += 1.f; }
#pragma unroll
    for (int o = 32; o; o >>= 1) { s += __shfl_xor(s, o); c += __shfl_xor(c, o); }
    if (c == cprev) break;
    tau = (s - 1.0f) / c; cprev = c;
  }
  float acc_o = 0.f;
  float p0 = v0 - tau, p1 = v1 - tau, p2 = v2 - tau, p3 = v3 - tau;
#pragma unroll
  for (int q = 0; q < 4; ++q) {
    float p = q == 0 ? p0 : (q == 1 ? p1 : (q == 2 ? p2 : p3));
    int jj = q == 0 ? j0 : (q == 1 ? j1 : (q == 2 ? j2 : j3));
    unsigned long long m = __ballot(p > 0.f);
    while (m) {
      int src = __ffsll((long long)m) - 1;
      m &= m - 1;
      float pj = __shfl(p, src);
      int j = __shfl(jj, src);
      acc_o += pj * (float)Vp[(size_t)j * 64 + lane];
    }
  }
  int rowg = (bh >> 3) * 2048 + n;          // [B][N] row
  AO[(size_t)rowg * 512 + (bh & 7) * 64 + lane] = (__bf16)acc_o;
}

// ---------------- kernel 2c: exact fallback, ONE ROW PER WAVE (parallel tail) ----
__global__ __launch_bounds__(512) void sparse_fb(
    const __bf16* __restrict__ Qh, const __bf16* __restrict__ Kh,
    const __bf16* __restrict__ Vh, __bf16* __restrict__ AO,
    const unsigned* __restrict__ ovf) {
  int lane = threadIdx.x & 63, wid = threadIdx.x >> 6;
  int rowid = blockIdx.x * 8 + wid;         // 4096 blocks x 8 waves = 32768 rows
  if (rowid >= 32768 || ovf[rowid] == 0) return;
  int bh = rowid >> 11, n = rowid & 2047;
  const __bf16* qp = Qh + ((size_t)bh * 2048 + n) * 64;
  bf8 qv[8];
#pragma unroll
  for (int j = 0; j < 8; ++j) qv[j] = *(const bf8*)(qp + j * 8);
  const __bf16* Kp = Kh + (size_t)bh * 2048 * 64;
  const __bf16* Vp = Vh + (size_t)bh * 2048 * 64;
  float z[32];
  for (int kk = 0; kk < 32; ++kk) {
    const __bf16* kr = Kp + (size_t)(kk * 64 + lane) * 64;
    float d = 0.f;
#pragma unroll
    for (int j = 0; j < 8; ++j) {
      bf8 kv = *(const bf8*)(kr + j * 8);
#pragma unroll
      for (int e = 0; e < 8; ++e) d += (float)qv[j][e] * (float)kv[e];
    }
    z[kk] = d;
  }
  float mx = z[0];
#pragma unroll
  for (int kk = 1; kk < 32; ++kk) mx = fmaxf(mx, z[kk]);
#pragma unroll
  for (int o = 32; o; o >>= 1) mx = fmaxf(mx, __shfl_xor(mx, o));
  float tau = mx - 1.0f, cprev = -1.0f;
  for (int it = 0; it < 48; ++it) {
    float s = 0.f, c = 0.f;
#pragma unroll
    for (int kk = 0; kk < 32; ++kk)
      if (z[kk] > tau) { s += z[kk]; c += 1.f; }
#pragma unroll
    for (int o = 32; o; o >>= 1) { s += __shfl_xor(s, o); c += __shfl_xor(c, o); }
    if (c == cprev) break;
    tau = (s - 1.0f) / c; cprev = c;
  }
  float acc_o = 0.f;
#pragma unroll
  for (int kk = 0; kk < 32; ++kk) {
    float p = z[kk] - tau;
    unsigned long long m = __ballot(p > 0.f);
    while (m) {
      int src = __ffsll((long long)m) - 1;
      m &= m - 1;
      float pj = __shfl(p, src);
      int j = kk * 64 + src;
      acc_o += pj * (float)Vp[(size_t)j * 64 + lane];
    }
  }
  int rowg = (bh >> 3) * 2048 + n;
  AO[(size_t)rowg * 512 + (bh & 7) * 64 + lane] = (__bf16)acc_o;
}

// ---------------- kernel 3: out = AO @ W_out + b_out.  128x128 tile, T14 pipeline ----
__global__ __launch_bounds__(256) void out_gemm(
    const __bf16* __restrict__ A, const __bf16* __restrict__ wot,
    const float* __restrict__ bias, float* __restrict__ out) {
  __shared__ __bf16 Asm[128 * 64];
  __shared__ __bf16 Bsm[128 * 64];
  int bid = blockIdx.x;
  int bn = bid & 3, bm = bid >> 2;          // 4 col-tiles x 32 row-tiles of 128
  int t = threadIdx.x, lane = t & 63, wid = t >> 6;
  int wy = wid >> 1, wx = wid & 1;
  int l15 = lane & 15, lg = lane >> 4;
  int sr = t >> 3, sc = t & 7;
  const __bf16* Ag = A   + (size_t)(bm * 128 + sr) * 512 + sc * 8;
  const __bf16* Bg = wot + (size_t)(bn * 128 + sr) * 512 + sc * 8;
  int swz = (sc * 16) ^ ((sr & 7) << 4);
  bf8 ra[4], rb[4];
#pragma unroll
  for (int j = 0; j < 4; ++j) {
    ra[j] = *(const bf8*)(Ag + (size_t)(j * 32) * 512);
    rb[j] = *(const bf8*)(Bg + (size_t)(j * 32) * 512);
  }
  f4 acc[4][4];
#pragma unroll
  for (int mt = 0; mt < 4; ++mt)
#pragma unroll
    for (int nt = 0; nt < 4; ++nt) acc[mt][nt] = (f4){0.f, 0.f, 0.f, 0.f};

  for (int ks = 0; ks < 8; ++ks) {
    __syncthreads();
#pragma unroll
    for (int j = 0; j < 4; ++j) {
      *(bf8*)((char*)Asm + (size_t)(j * 32 + sr) * 128 + swz) = ra[j];
      *(bf8*)((char*)Bsm + (size_t)(j * 32 + sr) * 128 + swz) = rb[j];
    }
    if (ks < 7) {
      const __bf16* Ag2 = Ag + (ks + 1) * 64;
      const __bf16* Bg2 = Bg + (ks + 1) * 64;
#pragma unroll
      for (int j = 0; j < 4; ++j) {
        ra[j] = *(const bf8*)(Ag2 + (size_t)(j * 32) * 512);
        rb[j] = *(const bf8*)(Bg2 + (size_t)(j * 32) * 512);
      }
    }
    __syncthreads();
#pragma unroll
    for (int kk = 0; kk < 2; ++kk) {
      bf8 af[4], bg[4];
#pragma unroll
      for (int mt = 0; mt < 4; ++mt) {
        int r = wy * 64 + mt * 16 + l15;
        af[mt] = *(const bf8*)((const char*)Asm + (size_t)r * 128 +
                               ((kk * 64 + lg * 16) ^ ((r & 7) << 4)));
      }
#pragma unroll
      for (int nt = 0; nt < 4; ++nt) {
        int r = wx * 64 + nt * 16 + l15;
        bg[nt] = *(const bf8*)((const char*)Bsm + (size_t)r * 128 +
                               ((kk * 64 + lg * 16) ^ ((r & 7) << 4)));
      }
#pragma unroll
      for (int mt = 0; mt < 4; ++mt)
#pragma unroll
        for (int nt = 0; nt < 4; ++nt)
          acc[mt][nt] = __builtin_amdgcn_mfma_f32_16x16x32_bf16(af[mt], bg[nt], acc[mt][nt], 0, 0, 0);
    }
  }
#pragma unroll
  for (int mt = 0; mt < 4; ++mt)
#pragma unroll
    for (int nt = 0; nt < 4; ++nt) {
      int col = bn * 128 + wx * 64 + nt * 16 + l15;
      float bv = bias[col];
#pragma unroll
      for (int i = 0; i < 4; ++i) {
        int row = bm * 128 + wy * 64 + mt * 16 + lg * 4 + i;
        out[(size_t)row * 512 + col] = acc[mt][nt][i] + bv;
      }
    }
}

extern "C" void kernel_launch(void* const* d_in, const int* in_sizes, int n_in,
                              void* d_out, int out_size, void* d_ws, size_t ws_size,
                              hipStream_t stream) {
  const float* x  = (const float*)d_in[0];
  const float* Wq = (const float*)d_in[1];
  const float* Wo = (const float*)d_in[2];
  const float* bo = (const float*)d_in[3];
  char* ws = (char*)d_ws;
  __bf16* xb  = (__bf16*)(ws + XB_OFF);
  __bf16* wqt = (__bf16*)(ws + WQT_OFF);
  __bf16* wot = (__bf16*)(ws + WOT_OFF);
  __bf16* Qh  = (__bf16*)(ws + Q_OFF);
  __bf16* Kh  = (__bf16*)(ws + K_OFF);
  __bf16* Vh  = (__bf16*)(ws + V_OFF);
  __bf16* AO  = (__bf16*)(ws + AO_OFF);
  unsigned* cd = (unsigned*)(ws + CAND_OFF);
  float* bm = (float*)(ws + BM_OFF);
  unsigned char* ob = (unsigned char*)(ws + OVB_OFF);
  unsigned* ov = (unsigned*)(ws + OVF_OFF);

  prep_kernel<<<(ROWS * DIM) / 256, 256, 0, stream>>>(x, Wq, Wo, xb, wqt, wot);
  qkv_gemm<<<32 * 12, 256, 0, stream>>>(xb, wqt, Qh, Kh, Vh);
  qk_gemm<<<4096, 256, 0, stream>>>(Qh, Kh, cd, bm, ob);
  sparse_pv<<<4096, 512, 0, stream>>>(cd, bm, ob, Vh, AO, ov);
  sparse_fb<<<4096, 512, 0, stream>>>(Qh, Kh, Vh, AO, ov);
  out_gemm<<<128, 256, 0, stream>>>(AO, wot, bo, (float*)d_out);
}

// Round 25
// 102.225 us; speedup vs baseline: 13.5617x; 1.5069x over previous
//
#include <hip/hip_runtime.h>

typedef __bf16 bf8 __attribute__((ext_vector_type(8)));
typedef float f4 __attribute__((ext_vector_type(4)));
typedef _Float16 h8 __attribute__((ext_vector_type(8)));
typedef _Float16 h2 __attribute__((ext_vector_type(2)));

// Problem constants (fixed by reference)
constexpr int BSZ = 2, NSEQ = 2048, DIM = 512, NH = 8, DH = 64, INNER = 512;
constexpr int ROWS = BSZ * NSEQ;          // 4096

// Workspace layout (bytes) — d_ws is >=268 MB (harness poison size)
constexpr size_t XB_OFF  = 0;                          // x cast bf16: 4 MB
constexpr size_t WQT_OFF = 4194304;                    // W_qkv^T bf16: 1.5 MB
constexpr size_t WOT_OFF = WQT_OFF + 1572864;          // W_out^T bf16: 0.5 MB
constexpr size_t Q_OFF   = WOT_OFF + 524288;           // Q/8 bf16 [16][2048][64]: 4 MB
constexpr size_t K_OFF   = Q_OFF + 4194304;            // K bf16: 4 MB
constexpr size_t V_OFF   = K_OFF + 4194304;            // V bf16: 4 MB
constexpr size_t AO_OFF  = V_OFF + 4194304;            // attn out bf16 [4096][512]: 4 MB
constexpr size_t SG_OFF  = AO_OFF + 4194304;           // S f16 [16][2048][2048]: 128 MB
constexpr size_t BM_OFF  = SG_OFF + 134217728;         // bmax f32 [16][2048][16]: 2 MB
// total ~152 MB

// ---------------- prep: cast x to bf16; transpose+cast W_qkv, W_out ----------------
__global__ __launch_bounds__(256) void prep_kernel(
    const float* __restrict__ x, const float* __restrict__ Wq, const float* __restrict__ Wo,
    __bf16* __restrict__ xb, __bf16* __restrict__ wqt, __bf16* __restrict__ wot) {
  int idx = blockIdx.x * 256 + threadIdx.x;
  if (idx < ROWS * DIM) xb[idx] = (__bf16)x[idx];
  if (idx < 3 * INNER * DIM) {            // wqt[n][k] = Wq[k][n]
    int n = idx >> 9, k = idx & 511;
    wqt[idx] = (__bf16)Wq[k * (3 * INNER) + n];
  }
  if (idx < INNER * DIM) {                // wot[n][k] = Wo[k][n]
    int n = idx >> 9, k = idx & 511;
    wot[idx] = (__bf16)Wo[k * DIM + n];
  }
}

// ---------------- kernel 1: qkv = x @ W_qkv -> Q/8,K,V.  128x128 tile, BK=64, ----
// T14 reg-staged LDS pipeline: issue loads for step k+1 before computing step k.
__global__ __launch_bounds__(256) void qkv_gemm(
    const __bf16* __restrict__ xb, const __bf16* __restrict__ wqt,
    __bf16* __restrict__ Qh, __bf16* __restrict__ Kh, __bf16* __restrict__ Vh) {
  __shared__ __bf16 Asm[128 * 64];          // byte = r*128 + (chbyte ^ ((r&7)<<4))
  __shared__ __bf16 Bsm[128 * 64];
  int bid = blockIdx.x;
  int bn = bid % 12, bm = bid / 12;         // 12 col-tiles x 32 row-tiles of 128
  int t = threadIdx.x, lane = t & 63, wid = t >> 6;
  int wy = wid >> 1, wx = wid & 1;
  int l15 = lane & 15, lg = lane >> 4;
  // staging geometry: thread t covers rows j*32+(t>>3), 16B chunk (t&7)
  int sr = t >> 3, sc = t & 7;
  const __bf16* Ag = xb  + (size_t)(bm * 128 + sr) * 512 + sc * 8;
  const __bf16* Bg = wqt + (size_t)(bn * 128 + sr) * 512 + sc * 8;
  int swz = (sc * 16) ^ ((sr & 7) << 4);    // (j*32 preserves r&7)
  bf8 ra[4], rb[4];
#pragma unroll
  for (int j = 0; j < 4; ++j) {
    ra[j] = *(const bf8*)(Ag + (size_t)(j * 32) * 512);
    rb[j] = *(const bf8*)(Bg + (size_t)(j * 32) * 512);
  }
  f4 acc[4][4];
#pragma unroll
  for (int mt = 0; mt < 4; ++mt)
#pragma unroll
    for (int nt = 0; nt < 4; ++nt) acc[mt][nt] = (f4){0.f, 0.f, 0.f, 0.f};

  for (int ks = 0; ks < 8; ++ks) {
    __syncthreads();
#pragma unroll
    for (int j = 0; j < 4; ++j) {
      *(bf8*)((char*)Asm + (size_t)(j * 32 + sr) * 128 + swz) = ra[j];
      *(bf8*)((char*)Bsm + (size_t)(j * 32 + sr) * 128 + swz) = rb[j];
    }
    if (ks < 7) {                           // issue next-tile loads; they fly during MFMA
      const __bf16* Ag2 = Ag + (ks + 1) * 64;
      const __bf16* Bg2 = Bg + (ks + 1) * 64;
#pragma unroll
      for (int j = 0; j < 4; ++j) {
        ra[j] = *(const bf8*)(Ag2 + (size_t)(j * 32) * 512);
        rb[j] = *(const bf8*)(Bg2 + (size_t)(j * 32) * 512);
      }
    }
    __syncthreads();
#pragma unroll
    for (int kk = 0; kk < 2; ++kk) {
      bf8 af[4], bg[4];
#pragma unroll
      for (int mt = 0; mt < 4; ++mt) {
        int r = wy * 64 + mt * 16 + l15;
        af[mt] = *(const bf8*)((const char*)Asm + (size_t)r * 128 +
                               ((kk * 64 + lg * 16) ^ ((r & 7) << 4)));
      }
#pragma unroll
      for (int nt = 0; nt < 4; ++nt) {
        int r = wx * 64 + nt * 16 + l15;
        bg[nt] = *(const bf8*)((const char*)Bsm + (size_t)r * 128 +
                               ((kk * 64 + lg * 16) ^ ((r & 7) << 4)));
      }
#pragma unroll
      for (int mt = 0; mt < 4; ++mt)
#pragma unroll
        for (int nt = 0; nt < 4; ++nt)
          acc[mt][nt] = __builtin_amdgcn_mfma_f32_16x16x32_bf16(af[mt], bg[nt], acc[mt][nt], 0, 0, 0);
    }
  }
  // epilogue: scatter into Q/8, K, V
#pragma unroll
  for (int mt = 0; mt < 4; ++mt)
#pragma unroll
    for (int nt = 0; nt < 4; ++nt) {
      int col = bn * 128 + wx * 64 + nt * 16 + l15;
      int which = col >> 9;                  // 0=q 1=k 2=v
      int inner = col & 511;
      int h = inner >> 6, d = inner & 63;
      __bf16* dst = which == 0 ? Qh : (which == 1 ? Kh : Vh);
      float scale = which == 0 ? 0.125f : 1.0f;
#pragma unroll
      for (int i = 0; i < 4; ++i) {
        int row = bm * 128 + wy * 64 + mt * 16 + lg * 4 + i;
        int b = row >> 11, n = row & 2047;
        dst[(((size_t)(b * 8 + h)) * 2048 + n) * 64 + d] = (__bf16)(acc[mt][nt][i] * scale);
      }
    }
}

// ---------------- kernel 2a: S = (Q/8) @ K^T + per-block row-max, all 16 heads ----
// K-tile LDS-staged once per block (shared by 4 waves); LDS reused for store repack.
// Grid 4096, XCD-swizzled so each XCD works on ~2 heads (K/Q panels stay in its L2).
__global__ __launch_bounds__(256) void qk_gemm(
    const __bf16* __restrict__ Qh, const __bf16* __restrict__ Kh,
    _Float16* __restrict__ Sg, float* __restrict__ bmax) {
  __shared__ char lds[32768];               // [0,16K): K-tile; later: ct[4][32][128]
  int bid = blockIdx.x;
  int lin = (bid & 7) * 512 + (bid >> 3);   // bijective XCD swizzle (4096 % 8 == 0)
  int bh = lin >> 8;                        // head 0..15
  int rt = (lin >> 4) & 15;                 // q row-tile (128)
  int colt = lin & 15;                      // k col-tile (128)
  int t = threadIdx.x, lane = t & 63, wid = t >> 6;
  int l15 = lane & 15, lg = lane >> 4;

  // stage K-tile [128 rows][64 dims] cooperatively, swizzled (rule #21 both-sides)
  {
    int sr = t >> 3, sc = t & 7;            // 32 rows/pass, full 128B rows coalesced
    const __bf16* Kg = Kh + ((size_t)bh * 2048 + colt * 128 + sr) * 64 + sc * 8;
    bf8 k0 = *(const bf8*)(Kg);
    bf8 k1 = *(const bf8*)(Kg + 32 * 64);
    bf8 k2 = *(const bf8*)(Kg + 64 * 64);
    bf8 k3 = *(const bf8*)(Kg + 96 * 64);
    int swz = (sc * 16) ^ ((sr & 7) << 4);  // +32j preserves r&7
    *(bf8*)(lds + (size_t)sr * 128 + swz) = k0;
    *(bf8*)(lds + (size_t)(sr + 32) * 128 + swz) = k1;
    *(bf8*)(lds + (size_t)(sr + 64) * 128 + swz) = k2;
    *(bf8*)(lds + (size_t)(sr + 96) * 128 + swz) = k3;
  }
  const __bf16* Qp = Qh + ((size_t)bh * 2048 + rt * 128 + wid * 32) * 64;
  bf8 aA0 = *(const bf8*)(Qp + l15 * 64 + lg * 8);
  bf8 aA1 = *(const bf8*)(Qp + l15 * 64 + 32 + lg * 8);
  bf8 aB0 = *(const bf8*)(Qp + (16 + l15) * 64 + lg * 8);
  bf8 aB1 = *(const bf8*)(Qp + (16 + l15) * 64 + 32 + lg * 8);
  __syncthreads();                          // K-tile ready

  f4 acc[2][8];
#pragma unroll
  for (int s = 0; s < 2; ++s)
#pragma unroll
    for (int j = 0; j < 8; ++j) acc[s][j] = (f4){0.f, 0.f, 0.f, 0.f};
#pragma unroll
  for (int ctj = 0; ctj < 8; ++ctj) {
    int r = ctj * 16 + l15;
    const char* kb = lds + (size_t)r * 128;
    int sw = (r & 7) << 4;
    bf8 b0 = *(const bf8*)(kb + ((lg * 16) ^ sw));        // dims lg*8..+8
    bf8 b1 = *(const bf8*)(kb + ((64 + lg * 16) ^ sw));   // dims 32+lg*8..+8
    acc[0][ctj] = __builtin_amdgcn_mfma_f32_16x16x32_bf16(aA0, b0, acc[0][ctj], 0, 0, 0);
    acc[0][ctj] = __builtin_amdgcn_mfma_f32_16x16x32_bf16(aA1, b1, acc[0][ctj], 0, 0, 0);
    acc[1][ctj] = __builtin_amdgcn_mfma_f32_16x16x32_bf16(aB0, b0, acc[1][ctj], 0, 0, 0);
    acc[1][ctj] = __builtin_amdgcn_mfma_f32_16x16x32_bf16(aB1, b1, acc[1][ctj], 0, 0, 0);
  }
  // per-block row-max (for sparse_pv's filter)
#pragma unroll
  for (int s = 0; s < 2; ++s)
#pragma unroll
    for (int i = 0; i < 4; ++i) {
      float rm = acc[s][0][i];
#pragma unroll
      for (int ctj = 1; ctj < 8; ++ctj) rm = fmaxf(rm, acc[s][ctj][i]);
#pragma unroll
      for (int o = 1; o < 16; o <<= 1) rm = fmaxf(rm, __shfl_xor(rm, o));
      if (l15 == 0) {
        int row = rt * 128 + wid * 32 + s * 16 + lg * 4 + i;
        bmax[((size_t)bh * 2048 + row) * 16 + colt] = rm;
      }
    }
  __syncthreads();                          // all waves done reading K-tile; reuse LDS
  _Float16 (*ct)[32][128] = (_Float16(*)[32][128])lds;
#pragma unroll
  for (int s = 0; s < 2; ++s)
#pragma unroll
    for (int ctj = 0; ctj < 8; ++ctj)
#pragma unroll
      for (int i = 0; i < 4; ++i) {
        int row = s * 16 + lg * 4 + i;
        int col = ctj * 16 + l15;
        ct[wid][row][col ^ (((row >> 2) & 3) << 4)] = (_Float16)acc[s][ctj][i];
      }
  int r4 = lane >> 4, ch = lane & 15;       // wave-private region: no barrier needed
  size_t srow0 = (size_t)bh * 2048 + rt * 128 + wid * 32;
#pragma unroll
  for (int it = 0; it < 8; ++it) {
    int r = it * 4 + r4;
    h8 v = *(const h8*)&ct[wid][r][(ch * 8) ^ (((r >> 2) & 3) << 4)];
    *(h8*)&Sg[(srow0 + r) * 2048 + colt * 128 + ch * 8] = v;
  }
}

// ---------------- kernel 2b: bmax-filtered sparsemax + sparse PV, one wave/row ----
// Tight tau bound via Michelot on block maxima; ballot compaction; group-skip gather.
__global__ __launch_bounds__(512, 8) void sparse_pv(
    const _Float16* __restrict__ Sg, const float* __restrict__ bmax,
    const __bf16* __restrict__ Vh, __bf16* __restrict__ AO) {
  __shared__ float candv[8][64];            // 2 KB
  __shared__ int   candj[8][64];            // 2 KB
  int lane = threadIdx.x & 63, wid = threadIdx.x >> 6;   // 8 waves
  int rowid = blockIdx.x * 8 + wid;         // 0..32767
  int bh = rowid >> 11, n = rowid & 2047;
  const _Float16* Srow = Sg + ((size_t)bh * 2048 + n) * 2048;
  const float* bmr = bmax + ((size_t)bh * 2048 + n) * 16;
  const __bf16* Vp = Vh + (size_t)bh * 2048 * 64;

  float bmv[16];
  *(f4*)&bmv[0]  = *(const f4*)&bmr[0];
  *(f4*)&bmv[4]  = *(const f4*)&bmr[4];
  *(f4*)&bmv[8]  = *(const f4*)&bmr[8];
  *(f4*)&bmv[12] = *(const f4*)&bmr[12];
  float gmax = bmv[0];
#pragma unroll
  for (int ct = 1; ct < 16; ++ct) gmax = fmaxf(gmax, bmv[ct]);

  // Tight lower bound on tau*: Michelot on the 16 block maxima (each is a real,
  // distinct row element => f_sub(t) <= f(t) => tau_sub <= tau*). Iterates from a
  // lower bound remain lower bounds, so a FIXED 3 iterations is valid.
  float tlb = gmax - 1.0f;                  // k=1 bound (gmax block always active)
#pragma unroll
  for (int it = 0; it < 3; ++it) {
    float s = 0.f, c = 0.f;
#pragma unroll
    for (int ct = 0; ct < 16; ++ct) {
      float v = bmv[ct];
      if (v > tlb) { s += v; c += 1.f; }
    }
    tlb = (s - 1.0f) / c;                   // c >= 1 always (see bound above)
  }
  // slack: bmax is f32 but S is f16-rounded (ulp ~0.002 at |z|~4; averaged bound
  // overshoot <= ~0.002). 0.012 is 5x margin.
  float tau0 = tlb - 0.012f;

  candv[wid][lane] = -1e30f;                // prefill so unwritten slots are inert
  candj[wid][lane] = 0;
  unsigned long long lmask = (1ULL << lane) - 1;   // lower-lane mask
  int base = 0; bool ovf = false;
#pragma unroll
  for (int ct = 0; ct < 16; ++ct) {
    if (bmv[ct] > tau0) {                   // row-uniform -> wave-uniform
      h2 zz = *(const h2*)&Srow[ct * 128 + lane * 2];
      float z0 = (float)zz[0], z1 = (float)zz[1];
      bool c0 = z0 > tau0, c1 = z1 > tau0;
      unsigned long long b0 = __ballot(c0), b1 = __ballot(c1);
      int n0 = __popcll(b0);
      int tot = n0 + __popcll(b1);
      if (base + tot <= 64) {
        if (c0) {
          int s0 = base + __popcll(b0 & lmask);
          candv[wid][s0] = z0; candj[wid][s0] = ct * 128 + lane * 2;
        }
        if (c1) {
          int s1 = base + n0 + __popcll(b1 & lmask);
          candv[wid][s1] = z1; candj[wid][s1] = ct * 128 + lane * 2 + 1;
        }
      } else ovf = true;
      base += tot;
    }
  }
  int total = base;
  float tau = tau0, acc_o = 0.f;
  if (!ovf) {
    if (total <= 32) {
      // register path: group-skipped broadcast loads, pure-VALU Michelot, gather
      f4 cv[8];
#pragma unroll
      for (int g = 0; g < 8; ++g)
        cv[g] = (g * 4 < total) ? *(const f4*)&candv[wid][g * 4]
                                : (f4){-1e30f, -1e30f, -1e30f, -1e30f};
      float cprev = -1.0f;
      for (int it = 0; it < 12; ++it) {
        float s = 0.f, c = 0.f;
#pragma unroll
        for (int g = 0; g < 8; ++g) {
          if (g * 4 < total) {              // wave-uniform
#pragma unroll
            for (int i = 0; i < 4; ++i) {
              float v = cv[g][i];
              if (v > tau) { s += v; c += 1.f; }
            }
          }
        }
        if (c == cprev) break;
        tau = (s - 1.0f) / c; cprev = c;
      }
      // gather: dead slots (candj=0) hit V row 0 -> L1 broadcast, p<=0 contributes 0
      const __bf16* vb = Vp + lane;
#pragma unroll
      for (int g = 0; g < 8; ++g) {
        if (g * 4 < total) {                // wave-uniform
          int j0 = candj[wid][g * 4 + 0];
          int j1 = candj[wid][g * 4 + 1];
          int j2 = candj[wid][g * 4 + 2];
          int j3 = candj[wid][g * 4 + 3];
          acc_o += fmaxf(cv[g][0] - tau, 0.f) * (float)vb[(size_t)j0 * 64];
          acc_o += fmaxf(cv[g][1] - tau, 0.f) * (float)vb[(size_t)j1 * 64];
          acc_o += fmaxf(cv[g][2] - tau, 0.f) * (float)vb[(size_t)j2 * 64];
          acc_o += fmaxf(cv[g][3] - tau, 0.f) * (float)vb[(size_t)j3 * 64];
        }
      }
    } else {
      // mid path (33..64): 1 cand/lane butterfly Michelot + ballot-shfl gather
      float v = candv[wid][lane];
      int jv = candj[wid][lane];
      bool valid = lane < total;
      float cprev = -1.0f;
      for (int it = 0; it < 24; ++it) {
        bool in = valid && (v > tau);
        float s = in ? v : 0.f, c = in ? 1.f : 0.f;
#pragma unroll
        for (int o = 32; o; o >>= 1) { s += __shfl_xor(s, o); c += __shfl_xor(c, o); }
        if (c == cprev) break;
        tau = (s - 1.0f) / c; cprev = c;
      }
      float p = valid ? v - tau : 0.f;
      unsigned long long m = __ballot(p > 0.f);
      while (m) {
        int src = __ffsll((long long)m) - 1;
        m &= m - 1;
        float pj = __shfl(p, src);
        int j = __shfl(jv, src);
        acc_o += pj * (float)Vp[(size_t)j * 64 + lane];
      }
    }
  } else {
    // fallback (rare): read full row, full-register Michelot from tau0 + ballot gather
    h8 zc[4];
#pragma unroll
    for (int r = 0; r < 4; ++r)
      zc[r] = *(const h8*)&Srow[r * 512 + lane * 8];
    float cprev = -1.0f;
    for (int it = 0; it < 48; ++it) {
      float s = 0.f, c = 0.f;
#pragma unroll
      for (int r = 0; r < 4; ++r)
#pragma unroll
        for (int i = 0; i < 8; ++i) {
          float zz = (float)zc[r][i];
          if (zz > tau) { s += zz; c += 1.f; }
        }
#pragma unroll
      for (int o = 32; o; o >>= 1) { s += __shfl_xor(s, o); c += __shfl_xor(c, o); }
      if (c == cprev) break;
      tau = (s - 1.0f) / c; cprev = c;
    }
#pragma unroll
    for (int r = 0; r < 4; ++r)
#pragma unroll
      for (int i = 0; i < 8; ++i) {
        float p = (float)zc[r][i] - tau;
        unsigned long long m = __ballot(p > 0.f);
        while (m) {
          int src = __ffsll((long long)m) - 1;
          m &= m - 1;
          float pj = __shfl(p, src);
          int j = r * 512 + src * 8 + i;
          acc_o += pj * (float)Vp[(size_t)j * 64 + lane];
        }
      }
  }
  int rowg = (bh >> 3) * 2048 + n;          // [B][N] row
  AO[(size_t)rowg * 512 + (bh & 7) * 64 + lane] = (__bf16)acc_o;
}

// ---------------- kernel 3: out = AO @ W_out + b_out.  128x128 tile, T14 pipeline ----
__global__ __launch_bounds__(256) void out_gemm(
    const __bf16* __restrict__ A, const __bf16* __restrict__ wot,
    const float* __restrict__ bias, float* __restrict__ out) {
  __shared__ __bf16 Asm[128 * 64];
  __shared__ __bf16 Bsm[128 * 64];
  int bid = blockIdx.x;
  int bn = bid & 3, bm = bid >> 2;          // 4 col-tiles x 32 row-tiles of 128
  int t = threadIdx.x, lane = t & 63, wid = t >> 6;
  int wy = wid >> 1, wx = wid & 1;
  int l15 = lane & 15, lg = lane >> 4;
  int sr = t >> 3, sc = t & 7;
  const __bf16* Ag = A   + (size_t)(bm * 128 + sr) * 512 + sc * 8;
  const __bf16* Bg = wot + (size_t)(bn * 128 + sr) * 512 + sc * 8;
  int swz = (sc * 16) ^ ((sr & 7) << 4);
  bf8 ra[4], rb[4];
#pragma unroll
  for (int j = 0; j < 4; ++j) {
    ra[j] = *(const bf8*)(Ag + (size_t)(j * 32) * 512);
    rb[j] = *(const bf8*)(Bg + (size_t)(j * 32) * 512);
  }
  f4 acc[4][4];
#pragma unroll
  for (int mt = 0; mt < 4; ++mt)
#pragma unroll
    for (int nt = 0; nt < 4; ++nt) acc[mt][nt] = (f4){0.f, 0.f, 0.f, 0.f};

  for (int ks = 0; ks < 8; ++ks) {
    __syncthreads();
#pragma unroll
    for (int j = 0; j < 4; ++j) {
      *(bf8*)((char*)Asm + (size_t)(j * 32 + sr) * 128 + swz) = ra[j];
      *(bf8*)((char*)Bsm + (size_t)(j * 32 + sr) * 128 + swz) = rb[j];
    }
    if (ks < 7) {
      const __bf16* Ag2 = Ag + (ks + 1) * 64;
      const __bf16* Bg2 = Bg + (ks + 1) * 64;
#pragma unroll
      for (int j = 0; j < 4; ++j) {
        ra[j] = *(const bf8*)(Ag2 + (size_t)(j * 32) * 512);
        rb[j] = *(const bf8*)(Bg2 + (size_t)(j * 32) * 512);
      }
    }
    __syncthreads();
#pragma unroll
    for (int kk = 0; kk < 2; ++kk) {
      bf8 af[4], bg[4];
#pragma unroll
      for (int mt = 0; mt < 4; ++mt) {
        int r = wy * 64 + mt * 16 + l15;
        af[mt] = *(const bf8*)((const char*)Asm + (size_t)r * 128 +
                               ((kk * 64 + lg * 16) ^ ((r & 7) << 4)));
      }
#pragma unroll
      for (int nt = 0; nt < 4; ++nt) {
        int r = wx * 64 + nt * 16 + l15;
        bg[nt] = *(const bf8*)((const char*)Bsm + (size_t)r * 128 +
                               ((kk * 64 + lg * 16) ^ ((r & 7) << 4)));
      }
#pragma unroll
      for (int mt = 0; mt < 4; ++mt)
#pragma unroll
        for (int nt = 0; nt < 4; ++nt)
          acc[mt][nt] = __builtin_amdgcn_mfma_f32_16x16x32_bf16(af[mt], bg[nt], acc[mt][nt], 0, 0, 0);
    }
  }
#pragma unroll
  for (int mt = 0; mt < 4; ++mt)
#pragma unroll
    for (int nt = 0; nt < 4; ++nt) {
      int col = bn * 128 + wx * 64 + nt * 16 + l15;
      float bv = bias[col];
#pragma unroll
      for (int i = 0; i < 4; ++i) {
        int row = bm * 128 + wy * 64 + mt * 16 + lg * 4 + i;
        out[(size_t)row * 512 + col] = acc[mt][nt][i] + bv;
      }
    }
}

extern "C" void kernel_launch(void* const* d_in, const int* in_sizes, int n_in,
                              void* d_out, int out_size, void* d_ws, size_t ws_size,
                              hipStream_t stream) {
  const float* x  = (const float*)d_in[0];
  const float* Wq = (const float*)d_in[1];
  const float* Wo = (const float*)d_in[2];
  const float* bo = (const float*)d_in[3];
  char* ws = (char*)d_ws;
  __bf16* xb  = (__bf16*)(ws + XB_OFF);
  __bf16* wqt = (__bf16*)(ws + WQT_OFF);
  __bf16* wot = (__bf16*)(ws + WOT_OFF);
  __bf16* Qh  = (__bf16*)(ws + Q_OFF);
  __bf16* Kh  = (__bf16*)(ws + K_OFF);
  __bf16* Vh  = (__bf16*)(ws + V_OFF);
  __bf16* AO  = (__bf16*)(ws + AO_OFF);
  _Float16* Sg = (_Float16*)(ws + SG_OFF);
  float* bm = (float*)(ws + BM_OFF);

  prep_kernel<<<(ROWS * DIM) / 256, 256, 0, stream>>>(x, Wq, Wo, xb, wqt, wot);
  qkv_gemm<<<32 * 12, 256, 0, stream>>>(xb, wqt, Qh, Kh, Vh);
  qk_gemm<<<4096, 256, 0, stream>>>(Qh, Kh, Sg, bm);
  sparse_pv<<<4096, 512, 0, stream>>>(Sg, bm, Vh, AO);
  out_gemm<<<128, 256, 0, stream>>>(AO, wot, bo, (float*)d_out);
}